// Round 3
// 5012.580 us; speedup vs baseline: 1.5243x; 1.5243x over previous
//
#include <hip/hip_runtime.h>
#include <hip/hip_cooperative_groups.h>
#include <math.h>

namespace cg = cooperative_groups;

#define HH 4096          // 64*64
#define NSLOT 520        // Phi snapshots (complex, 8192 floats each)
#define MAXATT 512

// ---- ws layout (float offsets) ---- (identical to proven v1)
#define OFF_A     0                              // A^0..A^7: 8*4096
#define OFF_PHI   (32768)                        // NSLOT * 8192 (re|im)
#define OFF_RE    (OFF_PHI + NSLOT*8192)         // legacy (unused now)
#define OFF_EY    (OFF_RE + 4*HH)                // EYre|EYim: 2*4096
#define OFF_Y     (OFF_EY + 2*HH)                // 2 bufs x (u 262144 | v 262144)
#define OFF_PART  (OFF_Y + 1048576)              // 64 partials
#define OFF_CTRL  (OFF_PART + 64)                // 32 scalars
#define OFF_REC   (OFF_CTRL + 32)                // 128 x 4 (step, tau, h, pad)
#define OFF_THETA (OFF_REC + 512)                // 128 x 4096 (Re Theta_t)

struct Coefs { float r[8], e[8], pa[8], pb[8], pc[8]; };

// ---------------------------------------------------------------------------
// Host: derive dopri5 polynomial coefficients (verified in v1).
// ---------------------------------------------------------------------------
static Coefs make_coefs() {
    static const double beta[6][6] = {
        {1./5, 0, 0, 0, 0, 0},
        {3./40, 9./40, 0, 0, 0, 0},
        {44./45, -56./15, 32./9, 0, 0, 0},
        {19372./6561, -25360./2187, 64448./6561, -212./729, 0, 0},
        {9017./3168, -355./33, 46732./5247, 49./176, -5103./18656, 0},
        {35./384, 0., 500./1113, 125./192, -2187./6784, 11./84}};
    static const double c_sol[7] = {35./384, 0., 500./1113, 125./192,
                                    -2187./6784, 11./84, 0.};
    static const double b_hat[7] = {1951./21600, 0., 22642./50085, 451./720,
                                    -12231./42400, 649./6300, 1./60};
    static const double c_mid[7] = {
        6025192743./30085553152./2, 0., 51252292925./65400821598./2,
        -2691868925./45128329728./2, 187940372067./1594534317056./2,
        -1776094331./19743644256./2, 11237099./235043384./2};
    double P[8][8] = {{0}};
    P[1][0] = 1.0;
    for (int s = 2; s <= 7; s++) {
        P[s][0] = 1.0;
        for (int l = 1; l < s; l++) {
            double bl = beta[s-2][l-1];
            for (int d = 0; d < 7; d++) P[s][d+1] += bl * P[l][d];
        }
    }
    double R[8] = {0}, E[8] = {0}, M[8] = {0}, WR[8] = {0};
    R[0] = 1.0; M[0] = 1.0;
    for (int s = 1; s <= 7; s++)
        for (int d = 0; d < 7; d++) {
            R[d+1] += c_sol[s-1] * P[s][d];
            E[d+1] += (c_sol[s-1] - b_hat[s-1]) * P[s][d];
            M[d+1] += c_mid[s-1] * P[s][d];
        }
    for (int d = 0; d < 7; d++) WR[d+1] = R[d];
    Coefs c;
    for (int d = 0; d < 8; d++) {
        double W = (d == 1) ? 1.0 : 0.0, I0 = (d == 0) ? 1.0 : 0.0;
        c.r[d] = (float)R[d];
        c.e[d] = (float)E[d];
        c.pa[d] = (float)(-2*W + 2*WR[d] -  8*I0 -  8*R[d] + 16*M[d]);
        c.pb[d] = (float)( 5*W - 3*WR[d] + 18*I0 + 14*R[d] - 32*M[d]);
        c.pc[d] = (float)(-4*W + 1*WR[d] - 11*I0 -  5*R[d] + 16*M[d]);
    }
    return c;
}

// ---------------------------------------------------------------------------
// 64x64 fp32 matmul on LDS operands (256 thr, 4x4 tile per thread).
// ---------------------------------------------------------------------------
__device__ __forceinline__ void mm64(const float* __restrict__ a,
                                     const float* __restrict__ b,
                                     float* __restrict__ dst, int ty, int tx) {
    float acc[4][4];
#pragma unroll
    for (int i = 0; i < 4; i++)
#pragma unroll
        for (int j = 0; j < 4; j++) acc[i][j] = 0.f;
    for (int k = 0; k < 64; k++) {
        float av[4];
#pragma unroll
        for (int i = 0; i < 4; i++) av[i] = a[(4*ty+i)*64 + k];
        const float4 bq = *(const float4*)&b[k*64 + 4*tx];
        float bv[4] = {bq.x, bq.y, bq.z, bq.w};
#pragma unroll
        for (int i = 0; i < 4; i++)
#pragma unroll
            for (int j = 0; j < 4; j++) acc[i][j] += av[i]*bv[j];
    }
#pragma unroll
    for (int i = 0; i < 4; i++)
#pragma unroll
        for (int j = 0; j < 4; j++) dst[(4*ty+i)*64 + 4*tx + j] = acc[i][j];
}

// ---------------------------------------------------------------------------
__global__ __launch_bounds__(64) void k_zero(float* __restrict__ ws) {
    int t = threadIdx.x;
    if (t < 32) ws[OFF_CTRL + t] = 0.f;
}

// Build symmetric A from tril params; A^0..A^7 into ws; Phi slot0 = (I,0).
__global__ __launch_bounds__(256) void k_prep(const float* __restrict__ tri,
                                              float* __restrict__ ws) {
    __shared__ float sA[HH], sB[HH], sC[HH];
    const int tid = threadIdx.x;
    for (int l = tid; l < HH; l += 256) {
        int r = l >> 6, c = l & 63;
        int i = r > c ? r : c, j = r > c ? c : r;
        sA[l] = tri[(i*(i+1))/2 + j];          // tril_indices: idx(r,c)=r(r+1)/2+c
        float id = (r == c) ? 1.f : 0.f;
        ws[OFF_A + l] = id;                    // A^0 = I
        ws[OFF_PHI + l] = id;                  // Phi0 re = I
        ws[OFF_PHI + HH + l] = 0.f;            // Phi0 im = 0
    }
    __syncthreads();
    for (int l = tid; l < HH; l += 256) ws[OFF_A + HH + l] = sA[l];  // A^1
    const int ty = tid >> 4, tx = tid & 15;
    float* bufs[2] = {sB, sC};
    float* cur = sA;
    for (int d = 2; d <= 7; d++) {
        float* dst = bufs[d & 1];
        mm64(cur, sA, dst, ty, tx);
        __syncthreads();
        for (int l = tid; l < HH; l += 256) ws[OFF_A + d*HH + l] = dst[l];
        __syncthreads();
        cur = dst;
    }
}

// ---------------------------------------------------------------------------
// Init: y0 dense (u=x, v=0) into buf0; norms for Hairer initial-step.
// (v1 verbatim)
// ---------------------------------------------------------------------------
__global__ __launch_bounds__(256) void k_initdense(const float* __restrict__ x,
                                                   float* __restrict__ ws) {
    __shared__ float xs[64*68];
    __shared__ float m1[HH], m2[HH];
    __shared__ float red[256];
    const int tid = threadIdx.x;
    const int r0 = blockIdx.x * 64;
    const float4* xg = (const float4*)(x + (size_t)r0*64);
    for (int q = tid; q < 1024; q += 256) {
        float4 vv = xg[q];
        *(float4*)&xs[(q>>4)*68 + (q&15)*4] = vv;
    }
    for (int q = tid; q < 1024; q += 256) {
        ((float4*)m1)[q] = ((const float4*)(ws + OFF_A + HH))[q];
        ((float4*)m2)[q] = ((const float4*)(ws + OFF_A + 2*HH))[q];
    }
    __syncthreads();
    const int ty = tid >> 4, tx = tid & 15;
    float a1[4][4], a2[4][4];
#pragma unroll
    for (int i = 0; i < 4; i++)
#pragma unroll
        for (int j = 0; j < 4; j++) { a1[i][j] = 0.f; a2[i][j] = 0.f; }
    for (int k = 0; k < 64; k++) {
        float xv[4];
#pragma unroll
        for (int i = 0; i < 4; i++) xv[i] = xs[(4*ty+i)*68 + k];
        const float4 b1 = *(const float4*)&m1[k*64 + 4*tx];
        const float4 b2 = *(const float4*)&m2[k*64 + 4*tx];
        float bv1[4] = {b1.x, b1.y, b1.z, b1.w};
        float bv2[4] = {b2.x, b2.y, b2.z, b2.w};
#pragma unroll
        for (int i = 0; i < 4; i++)
#pragma unroll
            for (int j = 0; j < 4; j++) {
                a1[i][j] += xv[i]*bv1[j];
                a2[i][j] += xv[i]*bv2[j];
            }
    }
    float s0 = 0.f, s1 = 0.f, s2 = 0.f;
#pragma unroll
    for (int i = 0; i < 4; i++)
#pragma unroll
        for (int j = 0; j < 4; j++) {
            int rr = 4*ty + i, cc = 4*tx + j;
            float xval = xs[rr*68 + cc];
            float sc = 1e-3f * (1.f + fabsf(xval));
            float t0 = xval / sc;      s0 += t0*t0;
            float t1 = a1[i][j] * 1e3f; s1 += t1*t1;
            float t2 = a2[i][j] / sc;  s2 += t2*t2;
            size_t off = (size_t)(r0 + rr)*64 + cc;
            ws[OFF_Y + off] = xval;            // u0, buf0
            ws[OFF_Y + 262144 + off] = 0.f;    // v0, buf0
        }
    float sums[3] = {s0, s1, s2};
    for (int q = 0; q < 3; q++) {
        red[tid] = sums[q];
        __syncthreads();
        for (int w = 128; w > 0; w >>= 1) {
            if (tid < w) red[tid] += red[tid + w];
            __syncthreads();
        }
        if (tid == 0) atomicAdd(&ws[OFF_CTRL + 10 + q], red[0]);
        __syncthreads();
    }
}

// Hairer initial step (v1 verbatim).
__global__ void k_initctrl(float* __restrict__ ws) {
    float d0 = sqrtf(ws[OFF_CTRL+10]);
    float d1 = sqrtf(ws[OFF_CTRL+11]);
    float d2 = sqrtf(ws[OFF_CTRL+12]);
    float h0 = ((d0 < 1e-5f) || (d1 < 1e-5f)) ? 1e-6f : 0.01f*d0/d1;
    float h1;
    if ((d1 <= 1e-15f) && (d2 <= 1e-15f)) h1 = fmaxf(1e-6f, h0*1e-3f);
    else h1 = powf(0.01f / fmaxf(d1, d2), 0.2f);
    float dt = fminf(100.f*h0, h1);
    float* cf = ws + OFF_CTRL;
    int* ci = (int*)cf;
    cf[0] = 1.0f;   // t
    cf[1] = dt;     // h
    cf[2] = 2.0f;   // next target
    ci[4] = 0; ci[5] = 0; ci[6] = 0; ci[7] = 0;
    ci[8] = 1;      // target idx
    float* rc = ws + OFF_REC;   // target 0 = y0: step 0, tau 0
    rc[0] = 0.f; rc[1] = 0.f; rc[2] = 1.f; rc[3] = 0.f;
}

// ---------------------------------------------------------------------------
// Integrator v4 = v1 dataflow with TWO grid.syncs per attempt:
//  small+localsums(16 blk) -> sync -> dense(64 blk) -> sync -> replicated ctrl.
//  Delta vs v1 (proven): (a) R/E weighted sums computed locally inside the
//  small phase (into the same mats LDS slots v1 staged them to) instead of a
//  serial block-0 global compute_sums; (b) controller replicated in every
//  block's tid0 from the same 64 partials after grid.sync (bit-identical
//  decisions; only block 0 writes REC). Everything else is v1 verbatim.
// ---------------------------------------------------------------------------
__global__ __launch_bounds__(256) void k_integrate(const float* __restrict__ x,
                                                   float* __restrict__ ws,
                                                   Coefs C) {
    __shared__ float xs[64*68];
    __shared__ float mats[4*HH];
    __shared__ float red[256];
    __shared__ float bcf[4];
    cg::grid_group grid = cg::this_grid();
    const int tid = threadIdx.x;
    const int bid = blockIdx.x;
    const int ty = tid >> 4, tx = tid & 15;

    const int r0 = bid * 64;
    const float4* xg = (const float4*)(x + (size_t)r0*64);
    for (int q = tid; q < 1024; q += 256) {
        float4 vv = xg[q];
        *(float4*)&xs[(q>>4)*68 + (q&15)*4] = vv;
    }

    // replicated controller state
    float h    = ws[OFF_CTRL + 1];
    float t_   = ws[OFF_CTRL + 0];   // used by tid0 only
    float ntgt = ws[OFF_CTRL + 2];   // used by tid0 only
    int tgi = 1, na = 0, att = 0, ybuf = 0;
    __syncthreads();

    for (int iter = 0; iter < MAXATT; iter++) {
        // ---- phase small: Phi1 = Phi_na @ R(h), EY = Phi_na @ E(h) ----
        if (bid < 16) {
            const int o = bid & 3;
            const int slab = (bid >> 2) * 16;
            float* sa1 = mats;
            float* sa2 = mats + 1024;
            float* sbA = mats + 2048;        // re-combo (Rre or Ere)
            float* sbB = mats + 2048 + HH;   // im-combo (Rim or Eim)
            // local weighted sums (v1's compute_sums, one coef set, into LDS)
            {
                const float* coef = (o >= 2) ? C.e : C.r;
                float w[8];
                float hp = 1.f;
#pragma unroll
                for (int d = 0; d < 8; d++) { w[d] = coef[d]*hp; hp *= h; }
                const float4* A4 = (const float4*)(ws + OFF_A);
#pragma unroll
                for (int g = 0; g < 4; g++) {
                    const int q = tid + 256*g;
                    float4 re = {0,0,0,0}, im = {0,0,0,0};
#pragma unroll
                    for (int d = 0; d < 8; d++) {
                        float4 a = A4[d*1024 + q];
                        float cw = w[d];
                        if ((d & 3) >= 2) cw = -cw;     // i^2=-1, i^3=-i
                        if ((d & 1) == 0) {
                            re.x += cw*a.x; re.y += cw*a.y;
                            re.z += cw*a.z; re.w += cw*a.w;
                        } else {
                            im.x += cw*a.x; im.y += cw*a.y;
                            im.z += cw*a.z; im.w += cw*a.w;
                        }
                    }
                    *(float4*)&sbA[4*q] = re;
                    *(float4*)&sbB[4*q] = im;
                }
            }
            // stage this block's 16 Phi rows (slot na)
            const float* Pre = ws + OFF_PHI + (size_t)na*8192;
            const float* Pim = Pre + HH;
            for (int q = tid; q < 1024; q += 256) {
                sa1[q] = Pre[slab*64 + q];
                sa2[q] = Pim[slab*64 + q];
            }
            __syncthreads();
            const float *B1, *B2;
            float sgn;
            if (o == 0)      { B1 = sbA; B2 = sbB; sgn = -1.f; }
            else if (o == 1) { B1 = sbB; B2 = sbA; sgn =  1.f; }
            else if (o == 2) { B1 = sbA; B2 = sbB; sgn = -1.f; }
            else             { B1 = sbB; B2 = sbA; sgn =  1.f; }
            float* dst;
            if (o == 0)      dst = ws + OFF_PHI + (size_t)(na+1)*8192;
            else if (o == 1) dst = ws + OFF_PHI + (size_t)(na+1)*8192 + HH;
            else if (o == 2) dst = ws + OFF_EY;
            else             dst = ws + OFF_EY + HH;
            for (int e = tid; e < 1024; e += 256) {
                int rr = e >> 6, cc = e & 63;
                float acc = 0.f;
                for (int k = 0; k < 64; k++)
                    acc += sa1[rr*64+k]*B1[k*64+cc] + sgn*sa2[rr*64+k]*B2[k*64+cc];
                dst[(size_t)(slab+rr)*64 + cc] = acc;
            }
        }
        grid.sync();
        // ---- phase dense (v1 verbatim; replicated ybuf/na) ----
        {
            const float* P1re = ws + OFF_PHI + (size_t)(na+1)*8192;
            for (int q = tid; q < 1024; q += 256) {
                ((float4*)mats)[q]          = ((const float4*)P1re)[q];
                ((float4*)(mats + HH))[q]   = ((const float4*)(P1re + HH))[q];
                ((float4*)(mats + 2*HH))[q] = ((const float4*)(ws + OFF_EY))[q];
                ((float4*)(mats + 3*HH))[q] = ((const float4*)(ws + OFF_EY + HH))[q];
            }
            __syncthreads();
            float au[4][4], av_[4][4], ae[4][4], af_[4][4];
#pragma unroll
            for (int i = 0; i < 4; i++)
#pragma unroll
                for (int j = 0; j < 4; j++) {
                    au[i][j] = 0.f; av_[i][j] = 0.f; ae[i][j] = 0.f; af_[i][j] = 0.f;
                }
            for (int k = 0; k < 64; k++) {
                float xv[4];
#pragma unroll
                for (int i = 0; i < 4; i++) xv[i] = xs[(4*ty+i)*68 + k];
                const float4 b0 = *(const float4*)&mats[k*64 + 4*tx];
                const float4 b1 = *(const float4*)&mats[HH + k*64 + 4*tx];
                const float4 b2 = *(const float4*)&mats[2*HH + k*64 + 4*tx];
                const float4 b3 = *(const float4*)&mats[3*HH + k*64 + 4*tx];
                float v0[4] = {b0.x, b0.y, b0.z, b0.w};
                float v1[4] = {b1.x, b1.y, b1.z, b1.w};
                float v2[4] = {b2.x, b2.y, b2.z, b2.w};
                float v3[4] = {b3.x, b3.y, b3.z, b3.w};
#pragma unroll
                for (int i = 0; i < 4; i++)
#pragma unroll
                    for (int j = 0; j < 4; j++) {
                        au[i][j]  += xv[i]*v0[j];
                        av_[i][j] += xv[i]*v1[j];
                        ae[i][j]  += xv[i]*v2[j];
                        af_[i][j] += xv[i]*v3[j];
                    }
            }
            const float* yu0 = ws + OFF_Y + (size_t)ybuf*524288;
            const float* yv0 = yu0 + 262144;
            float* yu1 = ws + OFF_Y + (size_t)(1-ybuf)*524288;
            float* yv1 = yu1 + 262144;
            float s = 0.f;
#pragma unroll
            for (int i = 0; i < 4; i++)
#pragma unroll
                for (int j = 0; j < 4; j++) {
                    size_t off = (size_t)(r0 + 4*ty + i)*64 + (4*tx + j);
                    float u1 = au[i][j], v1 = av_[i][j];
                    float u0 = yu0[off], v0 = yv0[off];
                    float tu = 1e-3f + 1e-3f*fmaxf(fabsf(u0), fabsf(u1));
                    float tv = 1e-3f + 1e-3f*fmaxf(fabsf(v0), fabsf(v1));
                    float ru = ae[i][j]/tu, rv = af_[i][j]/tv;
                    s += ru*ru + rv*rv;
                    yu1[off] = u1;
                    yv1[off] = v1;
                }
            red[tid] = s;
            __syncthreads();
            for (int w = 128; w > 0; w >>= 1) {
                if (tid < w) red[tid] += red[tid + w];
                __syncthreads();
            }
            if (tid == 0) ws[OFF_PART + bid] = red[0];
        }
        grid.sync();
        // ---- phase ctrl: replicated in every block's tid0 (v1 arithmetic) --
        if (tid == 0) {
            float S = 0.f;
            for (int q = 0; q < 64; q++) S += ws[OFF_PART + q];
            float mer = S / 524288.f;           // mean over raveled (u,v)
            bool acc = (mer <= 1.0f);
            float fac = 0.9f * powf(sqrtf(mer), -0.2f);   // safety*rms^{-1/5}
            float lo = acc ? 1.0f : 0.2f;                 // dfactor
            fac = fminf(10.0f, fmaxf(fac, lo));           // ifactor
            float hnew = h * fac;
            int dn = 0;
            if (acc) {
                float tnew = t_ + h;                      // fp32, as jax
                int step0 = na;
                while (tgi < 128 && ntgt <= tnew) {
                    if (bid == 0) {
                        float* rc = ws + OFF_REC + 4*tgi;
                        rc[0] = (float)step0;
                        rc[1] = (ntgt - t_) / (tnew - t_);
                        rc[2] = h; rc[3] = 0.f;
                    }
                    ntgt += 1.0f;
                    tgi++;
                }
                t_ = tnew;
                if (tgi >= 128) dn = 1;
            }
            att++;
            if (att >= MAXATT || na + (acc ? 1 : 0) + 1 >= NSLOT) dn = 1;
            bcf[0] = hnew; bcf[1] = acc ? 1.f : 0.f; bcf[2] = (float)dn;
        }
        __syncthreads();
        h = bcf[0];
        if (bcf[1] != 0.f) { ybuf ^= 1; na++; }
        if (bcf[2] != 0.f) break;
    }
}

// Theta_t = Phi_step * (tau^4 Pa + tau^3 Pb + tau^2 Pc + tau W + 1)(W), Re only.
__global__ __launch_bounds__(256) void k_make_theta(float* __restrict__ ws,
                                                    Coefs C) {
    __shared__ float sre[HH], simm[HH], pre[HH], pim[HH];
    const int tid = threadIdx.x;
    const int t = blockIdx.x;
    const float* rc = ws + OFF_REC + 4*t;
    int step = (int)rc[0];
    if (step < 0) step = 0;
    if (step >= NSLOT) step = NSLOT - 1;
    const float tau = rc[1], h = rc[2];
    float hp[8];
    hp[0] = 1.f;
#pragma unroll
    for (int d = 1; d < 8; d++) hp[d] = hp[d-1]*h;
    float t2 = tau*tau, t3 = t2*tau, t4 = t3*tau;
    float wre[8], wim[8];
#pragma unroll
    for (int d = 0; d < 8; d++) {
        float sd = t4*C.pa[d] + t3*C.pb[d] + t2*C.pc[d];
        if (d == 1) sd += tau;
        if (d == 0) sd += 1.f;
        float w = sd * hp[d];
        int m = d & 3;
        wre[d] = (m == 0) ? w : (m == 2 ? -w : 0.f);
        wim[d] = (m == 1) ? w : (m == 3 ? -w : 0.f);
    }
    const float* phre = ws + OFF_PHI + (size_t)step*8192;
    const float* phim = phre + HH;
    for (int e = tid; e < HH; e += 256) {
        float are = 0.f, aim = 0.f;
#pragma unroll
        for (int d = 0; d < 8; d++) {
            float ad = ws[OFF_A + d*HH + e];
            are += wre[d]*ad;
            aim += wim[d]*ad;
        }
        sre[e] = are;
        simm[e] = aim;
        pre[e] = phre[e];
        pim[e] = phim[e];
    }
    __syncthreads();
    for (int e = tid; e < HH; e += 256) {
        int rr = e >> 6, cc = e & 63;
        float acc = 0.f;
        for (int k = 0; k < 64; k++)
            acc += pre[rr*64+k]*sre[k*64+cc] - pim[rr*64+k]*simm[k*64+cc];
        ws[OFF_THETA + (size_t)t*HH + e] = acc;
    }
}

// out[b, t, :] = x[b, :] @ Theta_t   (128 rows x one t per block)
__global__ __launch_bounds__(256) void k_out(const float* __restrict__ x,
                                             const float* __restrict__ ws,
                                             float* __restrict__ out) {
    __shared__ float xs[128*68];
    __shared__ float ct[HH];
    const int tid = threadIdx.x;
    const int b0 = blockIdx.x * 128;
    const int t = blockIdx.y;
    const float4* xg4 = (const float4*)(x + (size_t)b0*64);
    for (int i4 = tid; i4 < 2048; i4 += 256) {
        float4 vv = xg4[i4];
        *(float4*)&xs[(i4>>4)*68 + (i4&15)*4] = vv;
    }
    const float4* cg4 = (const float4*)(ws + OFF_THETA + (size_t)t*HH);
    for (int i4 = tid; i4 < 1024; i4 += 256) ((float4*)ct)[i4] = cg4[i4];
    __syncthreads();
    const int ty = tid >> 4, tx = tid & 15;
    float acc[8][4];
#pragma unroll
    for (int i = 0; i < 8; i++)
#pragma unroll
        for (int c = 0; c < 4; c++) acc[i][c] = 0.f;
    for (int kg = 0; kg < 16; kg++) {
        const int k0 = kg*4;
        float av[8][4];
#pragma unroll
        for (int i = 0; i < 8; i++) {
            float4 tq = *(const float4*)&xs[(ty + 16*i)*68 + k0];
            av[i][0] = tq.x; av[i][1] = tq.y; av[i][2] = tq.z; av[i][3] = tq.w;
        }
        float bv[4][4];
#pragma unroll
        for (int kk = 0; kk < 4; kk++) {
            float4 tq = *(const float4*)&ct[(k0+kk)*64 + 4*tx];
            bv[kk][0] = tq.x; bv[kk][1] = tq.y; bv[kk][2] = tq.z; bv[kk][3] = tq.w;
        }
#pragma unroll
        for (int i = 0; i < 8; i++)
#pragma unroll
            for (int c = 0; c < 4; c++)
#pragma unroll
                for (int kk = 0; kk < 4; kk++)
                    acc[i][c] += av[i][kk]*bv[kk][c];
    }
#pragma unroll
    for (int i = 0; i < 8; i++) {
        int row = b0 + ty + 16*i;
        size_t off = ((size_t)row*128 + t)*64 + 4*tx;
        float4 vv = {acc[i][0], acc[i][1], acc[i][2], acc[i][3]};
        *(float4*)&out[off] = vv;
    }
}

extern "C" void kernel_launch(void* const* d_in, const int* in_sizes, int n_in,
                              void* d_out, int out_size, void* d_ws, size_t ws_size,
                              hipStream_t stream) {
    const float* x = (const float*)d_in[0];
    const float* tri = (const float*)d_in[1];
    float* out = (float*)d_out;
    float* ws = (float*)d_ws;
    Coefs C = make_coefs();

    hipLaunchKernelGGL(k_zero, dim3(1), dim3(64), 0, stream, ws);
    hipLaunchKernelGGL(k_prep, dim3(1), dim3(256), 0, stream, tri, ws);
    hipLaunchKernelGGL(k_initdense, dim3(64), dim3(256), 0, stream, x, ws);
    hipLaunchKernelGGL(k_initctrl, dim3(1), dim3(1), 0, stream, ws);
    void* args[3] = {(void*)&x, (void*)&ws, (void*)&C};
    hipLaunchCooperativeKernel((void*)k_integrate, dim3(64), dim3(256), args, 0,
                               stream);
    hipLaunchKernelGGL(k_make_theta, dim3(128), dim3(256), 0, stream, ws, C);
    hipLaunchKernelGGL(k_out, dim3(32, 128), dim3(256), 0, stream, x, ws, out);
}

// Round 5
// 4123.124 us; speedup vs baseline: 1.8531x; 1.2157x over previous
//
#include <hip/hip_runtime.h>
#include <hip/hip_cooperative_groups.h>
#include <math.h>

namespace cg = cooperative_groups;

#define HH 4096          // 64*64
#define NSLOT 520        // Phi snapshots (complex, 8192 floats each)
#define MAXATT 512

// ---- ws layout (float offsets) ----
#define OFF_A     0                              // A^0..A^7: 8*4096
#define OFF_PHI   (32768)                        // NSLOT * 8192 (re|im)
#define OFF_RE    (OFF_PHI + NSLOT*8192)         // now: partials dbuf 2x64
#define OFF_EY    (OFF_RE + 4*HH)                // legacy (unused)
#define OFF_Y     (OFF_EY + 2*HH)                // legacy (unused)
#define OFF_PART  (OFF_Y + 1048576)              // legacy
#define OFF_CTRL  (OFF_PART + 64)                // 32 scalars
#define OFF_REC   (OFF_CTRL + 32)                // 128 x 4 (step, tau, h, pad)
#define OFF_THETA (OFF_REC + 512)                // 128 x 4096 (Re Theta_t)

struct Coefs { float r[8], e[8], pa[8], pb[8], pc[8]; };

// ---------------------------------------------------------------------------
// Host: derive dopri5 polynomial coefficients (verified).
// ---------------------------------------------------------------------------
static Coefs make_coefs() {
    static const double beta[6][6] = {
        {1./5, 0, 0, 0, 0, 0},
        {3./40, 9./40, 0, 0, 0, 0},
        {44./45, -56./15, 32./9, 0, 0, 0},
        {19372./6561, -25360./2187, 64448./6561, -212./729, 0, 0},
        {9017./3168, -355./33, 46732./5247, 49./176, -5103./18656, 0},
        {35./384, 0., 500./1113, 125./192, -2187./6784, 11./84}};
    static const double c_sol[7] = {35./384, 0., 500./1113, 125./192,
                                    -2187./6784, 11./84, 0.};
    static const double b_hat[7] = {1951./21600, 0., 22642./50085, 451./720,
                                    -12231./42400, 649./6300, 1./60};
    static const double c_mid[7] = {
        6025192743./30085553152./2, 0., 51252292925./65400821598./2,
        -2691868925./45128329728./2, 187940372067./1594534317056./2,
        -1776094331./19743644256./2, 11237099./235043384./2};
    double P[8][8] = {{0}};
    P[1][0] = 1.0;
    for (int s = 2; s <= 7; s++) {
        P[s][0] = 1.0;
        for (int l = 1; l < s; l++) {
            double bl = beta[s-2][l-1];
            for (int d = 0; d < 7; d++) P[s][d+1] += bl * P[l][d];
        }
    }
    double R[8] = {0}, E[8] = {0}, M[8] = {0}, WR[8] = {0};
    R[0] = 1.0; M[0] = 1.0;
    for (int s = 1; s <= 7; s++)
        for (int d = 0; d < 7; d++) {
            R[d+1] += c_sol[s-1] * P[s][d];
            E[d+1] += (c_sol[s-1] - b_hat[s-1]) * P[s][d];
            M[d+1] += c_mid[s-1] * P[s][d];
        }
    for (int d = 0; d < 7; d++) WR[d+1] = R[d];
    Coefs c;
    for (int d = 0; d < 8; d++) {
        double W = (d == 1) ? 1.0 : 0.0, I0 = (d == 0) ? 1.0 : 0.0;
        c.r[d] = (float)R[d];
        c.e[d] = (float)E[d];
        c.pa[d] = (float)(-2*W + 2*WR[d] -  8*I0 -  8*R[d] + 16*M[d]);
        c.pb[d] = (float)( 5*W - 3*WR[d] + 18*I0 + 14*R[d] - 32*M[d]);
        c.pc[d] = (float)(-4*W + 1*WR[d] - 11*I0 -  5*R[d] + 16*M[d]);
    }
    return c;
}

// ---------------------------------------------------------------------------
// 64x64 fp32 matmul on LDS operands (256 thr, 4x4 tile per thread). (k_prep)
// ---------------------------------------------------------------------------
__device__ __forceinline__ void mm64(const float* __restrict__ a,
                                     const float* __restrict__ b,
                                     float* __restrict__ dst, int ty, int tx) {
    float acc[4][4];
#pragma unroll
    for (int i = 0; i < 4; i++)
#pragma unroll
        for (int j = 0; j < 4; j++) acc[i][j] = 0.f;
    for (int k = 0; k < 64; k++) {
        float av[4];
#pragma unroll
        for (int i = 0; i < 4; i++) av[i] = a[(4*ty+i)*64 + k];
        const float4 bq = *(const float4*)&b[k*64 + 4*tx];
        float bv[4] = {bq.x, bq.y, bq.z, bq.w};
#pragma unroll
        for (int i = 0; i < 4; i++)
#pragma unroll
            for (int j = 0; j < 4; j++) acc[i][j] += av[i]*bv[j];
    }
#pragma unroll
    for (int i = 0; i < 4; i++)
#pragma unroll
        for (int j = 0; j < 4; j++) dst[(4*ty+i)*64 + 4*tx + j] = acc[i][j];
}

// ---------------------------------------------------------------------------
__global__ __launch_bounds__(256) void k_zero(float* __restrict__ ws) {
    int t = threadIdx.x;
    if (t < 32) ws[OFF_CTRL + t] = 0.f;
    if (t < 128) {   // REC defaults: step 0, tau 0, h 1 -> Theta = I
        float* rc = ws + OFF_REC + 4*t;
        rc[0] = 0.f; rc[1] = 0.f; rc[2] = 1.f; rc[3] = 0.f;
    }
}

// Build symmetric A from tril params; A^0..A^7 into ws; Phi slot0 = (I,0).
__global__ __launch_bounds__(256) void k_prep(const float* __restrict__ tri,
                                              float* __restrict__ ws) {
    __shared__ float sA[HH], sB[HH], sC[HH];
    const int tid = threadIdx.x;
    for (int l = tid; l < HH; l += 256) {
        int r = l >> 6, c = l & 63;
        int i = r > c ? r : c, j = r > c ? c : r;
        sA[l] = tri[(i*(i+1))/2 + j];
        float id = (r == c) ? 1.f : 0.f;
        ws[OFF_A + l] = id;                    // A^0 = I
        ws[OFF_PHI + l] = id;                  // Phi0 re = I
        ws[OFF_PHI + HH + l] = 0.f;            // Phi0 im = 0
    }
    __syncthreads();
    for (int l = tid; l < HH; l += 256) ws[OFF_A + HH + l] = sA[l];  // A^1
    const int ty = tid >> 4, tx = tid & 15;
    float* bufs[2] = {sB, sC};
    float* cur = sA;
    for (int d = 2; d <= 7; d++) {
        float* dst = bufs[d & 1];
        mm64(cur, sA, dst, ty, tx);
        __syncthreads();
        for (int l = tid; l < HH; l += 256) ws[OFF_A + d*HH + l] = dst[l];
        __syncthreads();
        cur = dst;
    }
}

// ---------------------------------------------------------------------------
// Init: norms for Hairer initial-step only (y-state lives in k_integrate LDS).
// ---------------------------------------------------------------------------
__global__ __launch_bounds__(256) void k_initdense(const float* __restrict__ x,
                                                   float* __restrict__ ws) {
    __shared__ float xs[64*68];
    __shared__ float m1[HH], m2[HH];
    __shared__ float red[256];
    const int tid = threadIdx.x;
    const int r0 = blockIdx.x * 64;
    const float4* xg = (const float4*)(x + (size_t)r0*64);
    for (int q = tid; q < 1024; q += 256) {
        float4 vv = xg[q];
        *(float4*)&xs[(q>>4)*68 + (q&15)*4] = vv;
    }
    for (int q = tid; q < 1024; q += 256) {
        ((float4*)m1)[q] = ((const float4*)(ws + OFF_A + HH))[q];
        ((float4*)m2)[q] = ((const float4*)(ws + OFF_A + 2*HH))[q];
    }
    __syncthreads();
    const int ty = tid >> 4, tx = tid & 15;
    float a1[4][4], a2[4][4];
#pragma unroll
    for (int i = 0; i < 4; i++)
#pragma unroll
        for (int j = 0; j < 4; j++) { a1[i][j] = 0.f; a2[i][j] = 0.f; }
    for (int k = 0; k < 64; k++) {
        float xv[4];
#pragma unroll
        for (int i = 0; i < 4; i++) xv[i] = xs[(4*ty+i)*68 + k];
        const float4 b1 = *(const float4*)&m1[k*64 + 4*tx];
        const float4 b2 = *(const float4*)&m2[k*64 + 4*tx];
        float bv1[4] = {b1.x, b1.y, b1.z, b1.w};
        float bv2[4] = {b2.x, b2.y, b2.z, b2.w};
#pragma unroll
        for (int i = 0; i < 4; i++)
#pragma unroll
            for (int j = 0; j < 4; j++) {
                a1[i][j] += xv[i]*bv1[j];
                a2[i][j] += xv[i]*bv2[j];
            }
    }
    float s0 = 0.f, s1 = 0.f, s2 = 0.f;
#pragma unroll
    for (int i = 0; i < 4; i++)
#pragma unroll
        for (int j = 0; j < 4; j++) {
            int rr = 4*ty + i, cc = 4*tx + j;
            float xval = xs[rr*68 + cc];
            float sc = 1e-3f * (1.f + fabsf(xval));
            float t0 = xval / sc;      s0 += t0*t0;
            float t1 = a1[i][j] * 1e3f; s1 += t1*t1;
            float t2 = a2[i][j] / sc;  s2 += t2*t2;
        }
    float sums[3] = {s0, s1, s2};
    for (int q = 0; q < 3; q++) {
        red[tid] = sums[q];
        __syncthreads();
        for (int w = 128; w > 0; w >>= 1) {
            if (tid < w) red[tid] += red[tid + w];
            __syncthreads();
        }
        if (tid == 0) atomicAdd(&ws[OFF_CTRL + 10 + q], red[0]);
        __syncthreads();
    }
}

// Hairer initial step (verified).
__global__ void k_initctrl(float* __restrict__ ws) {
    float d0 = sqrtf(ws[OFF_CTRL+10]);
    float d1 = sqrtf(ws[OFF_CTRL+11]);
    float d2 = sqrtf(ws[OFF_CTRL+12]);
    float h0 = ((d0 < 1e-5f) || (d1 < 1e-5f)) ? 1e-6f : 0.01f*d0/d1;
    float h1;
    if ((d1 <= 1e-15f) && (d2 <= 1e-15f)) h1 = fmaxf(1e-6f, h0*1e-3f);
    else h1 = powf(0.01f / fmaxf(d1, d2), 0.2f);
    float dt = fminf(100.f*h0, h1);
    float* cf = ws + OFF_CTRL;
    cf[0] = 1.0f;   // t
    cf[1] = dt;     // h
    cf[2] = 2.0f;   // next target
    float* rc = ws + OFF_REC;   // target 0 = y0: step 0, tau 0
    rc[0] = 0.f; rc[1] = 0.f; rc[2] = 1.f; rc[3] = 0.f;
}

// One complex weighted sum into LDS: smat[0..HH)=re, smat[HH..2HH)=im
// of sum_d coef_d h^d (iA)^d.  (validated pattern: v4 small phase)
__device__ __forceinline__ void sums_pair(const float* __restrict__ ws,
                                          float* __restrict__ smat,
                                          float h, int tid,
                                          const float* __restrict__ coef) {
    float w[8];
    float hp = 1.f;
#pragma unroll
    for (int d = 0; d < 8; d++) { w[d] = coef[d]*hp; hp *= h; }
    const float4* A4 = (const float4*)(ws + OFF_A);
#pragma unroll
    for (int g = 0; g < 4; g++) {
        const int q = tid + 256*g;
        float4 re = {0,0,0,0}, im = {0,0,0,0};
#pragma unroll
        for (int d = 0; d < 8; d++) {
            float4 a = A4[d*1024 + q];
            float cw = w[d];
            if ((d & 3) >= 2) cw = -cw;     // i^2=-1, i^3=-i
            if ((d & 1) == 0) {
                re.x += cw*a.x; re.y += cw*a.y; re.z += cw*a.z; re.w += cw*a.w;
            } else {
                im.x += cw*a.x; im.y += cw*a.y; im.z += cw*a.z; im.w += cw*a.w;
            }
        }
        ((float4*)smat)[q] = re;
        ((float4*)(smat + HH))[q] = im;
    }
}

// (y0 @ (Mre + i Mim)) tile: aP = u0@Mre - v0@Mim, aQ = u0@Mim + v0@Mre.
// u0/v0 LDS stride 68 (padded); smat row-major 64.
__device__ __forceinline__ void cmm_tile(const float* __restrict__ u0,
                                         const float* __restrict__ v0,
                                         const float* __restrict__ smat,
                                         int ty, int tx,
                                         float aP[4][4], float aQ[4][4]) {
#pragma unroll
    for (int i = 0; i < 4; i++)
#pragma unroll
        for (int j = 0; j < 4; j++) { aP[i][j] = 0.f; aQ[i][j] = 0.f; }
#pragma unroll 2
    for (int k0 = 0; k0 < 64; k0 += 4) {
        float ua[4][4], va[4][4];
#pragma unroll
        for (int i = 0; i < 4; i++) {
            const float4 uq = *(const float4*)&u0[(4*ty+i)*68 + k0];
            const float4 vq = *(const float4*)&v0[(4*ty+i)*68 + k0];
            ua[i][0]=uq.x; ua[i][1]=uq.y; ua[i][2]=uq.z; ua[i][3]=uq.w;
            va[i][0]=vq.x; va[i][1]=vq.y; va[i][2]=vq.z; va[i][3]=vq.w;
        }
#pragma unroll
        for (int kk = 0; kk < 4; kk++) {
            const int k = k0 + kk;
            const float4 br = *(const float4*)&smat[k*64 + 4*tx];
            const float4 bi = *(const float4*)&smat[HH + k*64 + 4*tx];
            const float brv[4] = {br.x, br.y, br.z, br.w};
            const float biv[4] = {bi.x, bi.y, bi.z, bi.w};
#pragma unroll
            for (int i = 0; i < 4; i++) {
                const float ur = ua[i][kk], vr = va[i][kk];
#pragma unroll
                for (int j = 0; j < 4; j++) {
                    aP[i][j] += ur*brv[j] - vr*biv[j];
                    aQ[i][j] += ur*biv[j] + vr*brv[j];
                }
            }
        }
    }
}

// ---------------------------------------------------------------------------
// Integrator v5: 64 blocks x 256, ONE grid.sync per attempt, LDS 67.7 KB.
//  Per attempt: sums(E)+errpass -> sums(R)+steppass -> ratio/partial ->
//  grid.sync -> replicated ctrl -> accept(y in LDS) + lazy Phi (smat=Rc).
//  Cross-block data: only partials (dbuf by parity, sync-protected) and
//  Phi slabs (read post-kernel). y never leaves the block.
// ---------------------------------------------------------------------------
__global__ __launch_bounds__(256) void k_integrate(const float* __restrict__ x,
                                                   float* __restrict__ ws,
                                                   Coefs C) {
    __shared__ float u0[64*68], v0[64*68];   // y-state, padded stride 68
    __shared__ float smat[2*HH];             // one complex matrix (re|im)
    __shared__ float phre[256], phim[256];   // this block's 4 Phi rows (bid<16)
    __shared__ float red[4];
    __shared__ float bcf[4];                 // h, acc, done
    cg::grid_group grid = cg::this_grid();
    const int tid = threadIdx.x, bid = blockIdx.x;
    const int ty = tid >> 4, tx = tid & 15;
    const int r0 = bid * 64;
    float* part = ws + OFF_RE;               // 2 x 64 dbuf

    // y0 = (x rows, 0) into LDS
#pragma unroll
    for (int i = 0; i < 4; i++) {
        const float4 xv = *(const float4*)&x[(size_t)(r0 + 4*ty + i)*64 + 4*tx];
        *(float4*)&u0[(4*ty+i)*68 + 4*tx] = xv;
        float4 z = {0.f, 0.f, 0.f, 0.f};
        *(float4*)&v0[(4*ty+i)*68 + 4*tx] = z;
    }
    { int r = tid >> 6, c = tid & 63;
      phre[tid] = (4*bid + r == c) ? 1.f : 0.f; phim[tid] = 0.f; }

    // replicated controller state
    float h    = ws[OFF_CTRL + 1];
    float t_   = ws[OFF_CTRL + 0];
    float ntgt = ws[OFF_CTRL + 2];
    int tgi = 1, na = 0, att = 0;
    __syncthreads();

    for (int iter = 0; iter < MAXATT; iter++) {
        // ---- pass E: err = y0 @ Ec ----
        sums_pair(ws, smat, h, tid, C.e);
        __syncthreads();
        float aE[4][4], aF[4][4];
        cmm_tile(u0, v0, smat, ty, tx, aE, aF);
        __syncthreads();                       // smat reads done
        // ---- pass R: y1 = y0 @ Rc (smat keeps Rc for lazy Phi) ----
        sums_pair(ws, smat, h, tid, C.r);
        __syncthreads();
        float aU[4][4], aV[4][4];
        cmm_tile(u0, v0, smat, ty, tx, aU, aV);
        // ---- error ratio + reduce ----
        float s = 0.f;
#pragma unroll
        for (int i = 0; i < 4; i++)
#pragma unroll
            for (int j = 0; j < 4; j++) {
                const int off = (4*ty+i)*68 + 4*tx + j;
                const float tu = 1e-3f + 1e-3f*fmaxf(fabsf(u0[off]), fabsf(aU[i][j]));
                const float tv = 1e-3f + 1e-3f*fmaxf(fabsf(v0[off]), fabsf(aV[i][j]));
                const float ru = aE[i][j]/tu, rv = aF[i][j]/tv;
                s += ru*ru + rv*rv;
            }
#pragma unroll
        for (int off = 32; off; off >>= 1) s += __shfl_xor(s, off, 64);
        if ((tid & 63) == 0) red[tid >> 6] = s;
        __syncthreads();
        if (tid == 0) part[(iter & 1)*64 + bid] = red[0] + red[1] + red[2] + red[3];
        grid.sync();
        // ---- replicated controller (v4-validated arithmetic) ----
        if (tid == 0) {
            float S = 0.f;
            const int po = (iter & 1) * 64;
            for (int q = 0; q < 64; q++) S += part[po + q];
            float mer = S / 524288.f;           // mean over raveled (u,v)
            bool acc = (mer <= 1.0f);
            float fac = 0.9f * powf(sqrtf(mer), -0.2f);   // safety*rms^{-1/5}
            float lo = acc ? 1.0f : 0.2f;                 // dfactor
            fac = fminf(10.0f, fmaxf(fac, lo));           // ifactor
            float hnew = h * fac;
            int dn = 0;
            if (acc) {
                float tnew = t_ + h;                      // fp32, as jax
                int step0 = na;
                while (tgi < 128 && ntgt <= tnew) {
                    if (bid == 0) {
                        float* rc = ws + OFF_REC + 4*tgi;
                        rc[0] = (float)step0;
                        rc[1] = (ntgt - t_) / (tnew - t_);
                        rc[2] = h; rc[3] = 0.f;
                    }
                    ntgt += 1.0f;
                    tgi++;
                }
                t_ = tnew;
                if (tgi >= 128) dn = 1;
            }
            att++;
            if (att >= MAXATT || na + (acc ? 1 : 0) + 1 >= NSLOT) dn = 1;
            bcf[0] = hnew; bcf[1] = acc ? 1.f : 0.f; bcf[2] = (float)dn;
        }
        __syncthreads();
        const float hn = bcf[0];
        const bool acc = (bcf[1] != 0.f);
        const bool dn  = (bcf[2] != 0.f);
        // ---- apply accept: y0 <= y1 (LDS); lazy Phi (smat holds Rc) ----
        if (acc) {
#pragma unroll
            for (int i = 0; i < 4; i++)
#pragma unroll
                for (int j = 0; j < 4; j++) {
                    const int off = (4*ty+i)*68 + 4*tx + j;
                    u0[off] = aU[i][j];
                    v0[off] = aV[i][j];
                }
            na++;
        }
        const bool dophi = acc && (bid < 16);
        float nre = 0.f, nim = 0.f;
        if (dophi) {   // Phi_na = Phi_{na-1} @ Rc, rows 4bid..4bid+3
            const int r = tid >> 6, c = tid & 63;
            const float* pr = phre + r*64;
            const float* pi = phim + r*64;
#pragma unroll 8
            for (int k = 0; k < 64; k++) {
                nre += pr[k]*smat[k*64 + c] - pi[k]*smat[HH + k*64 + c];
                nim += pr[k]*smat[HH + k*64 + c] + pi[k]*smat[k*64 + c];
            }
        }
        __syncthreads();   // phre/smat reads done before overwrite
        if (dophi) {
            const int r = tid >> 6, c = tid & 63;
            phre[r*64 + c] = nre; phim[r*64 + c] = nim;
            const size_t go = OFF_PHI + (size_t)na*8192 + (size_t)(4*bid + r)*64 + c;
            ws[go] = nre; ws[go + HH] = nim;
        }
        h = hn;
        if (dn) break;
        // next iter's sums_pair(E) overwrite of smat is fenced by the
        // __syncthreads above (phi reads) + the one after sums_pair.
    }
}

// Theta_t = Phi_step * (tau^4 Pa + tau^3 Pb + tau^2 Pc + tau W + 1)(W), Re only.
__global__ __launch_bounds__(256) void k_make_theta(float* __restrict__ ws,
                                                    Coefs C) {
    __shared__ float sre[HH], simm[HH], pre[HH], pim[HH];
    const int tid = threadIdx.x;
    const int t = blockIdx.x;
    const float* rc = ws + OFF_REC + 4*t;
    int step = (int)rc[0];
    if (step < 0) step = 0;
    if (step >= NSLOT) step = NSLOT - 1;
    const float tau = rc[1], h = rc[2];
    float hp[8];
    hp[0] = 1.f;
#pragma unroll
    for (int d = 1; d < 8; d++) hp[d] = hp[d-1]*h;
    float t2 = tau*tau, t3 = t2*tau, t4 = t3*tau;
    float wre[8], wim[8];
#pragma unroll
    for (int d = 0; d < 8; d++) {
        float sd = t4*C.pa[d] + t3*C.pb[d] + t2*C.pc[d];
        if (d == 1) sd += tau;
        if (d == 0) sd += 1.f;
        float w = sd * hp[d];
        int m = d & 3;
        wre[d] = (m == 0) ? w : (m == 2 ? -w : 0.f);
        wim[d] = (m == 1) ? w : (m == 3 ? -w : 0.f);
    }
    const float* phre = ws + OFF_PHI + (size_t)step*8192;
    const float* phim = phre + HH;
    for (int e = tid; e < HH; e += 256) {
        float are = 0.f, aim = 0.f;
#pragma unroll
        for (int d = 0; d < 8; d++) {
            float ad = ws[OFF_A + d*HH + e];
            are += wre[d]*ad;
            aim += wim[d]*ad;
        }
        sre[e] = are;
        simm[e] = aim;
        pre[e] = phre[e];
        pim[e] = phim[e];
    }
    __syncthreads();
    for (int e = tid; e < HH; e += 256) {
        int rr = e >> 6, cc = e & 63;
        float acc = 0.f;
        for (int k = 0; k < 64; k++)
            acc += pre[rr*64+k]*sre[k*64+cc] - pim[rr*64+k]*simm[k*64+cc];
        ws[OFF_THETA + (size_t)t*HH + e] = acc;
    }
}

// out[b, t, :] = x[b, :] @ Theta_t   (128 rows x one t per block)
__global__ __launch_bounds__(256) void k_out(const float* __restrict__ x,
                                             const float* __restrict__ ws,
                                             float* __restrict__ out) {
    __shared__ float xs[128*68];
    __shared__ float ct[HH];
    const int tid = threadIdx.x;
    const int b0 = blockIdx.x * 128;
    const int t = blockIdx.y;
    const float4* xg4 = (const float4*)(x + (size_t)b0*64);
    for (int i4 = tid; i4 < 2048; i4 += 256) {
        float4 vv = xg4[i4];
        *(float4*)&xs[(i4>>4)*68 + (i4&15)*4] = vv;
    }
    const float4* cg4 = (const float4*)(ws + OFF_THETA + (size_t)t*HH);
    for (int i4 = tid; i4 < 1024; i4 += 256) ((float4*)ct)[i4] = cg4[i4];
    __syncthreads();
    const int ty = tid >> 4, tx = tid & 15;
    float acc[8][4];
#pragma unroll
    for (int i = 0; i < 8; i++)
#pragma unroll
        for (int c = 0; c < 4; c++) acc[i][c] = 0.f;
    for (int kg = 0; kg < 16; kg++) {
        const int k0 = kg*4;
        float av[8][4];
#pragma unroll
        for (int i = 0; i < 8; i++) {
            float4 tq = *(const float4*)&xs[(ty + 16*i)*68 + k0];
            av[i][0] = tq.x; av[i][1] = tq.y; av[i][2] = tq.z; av[i][3] = tq.w;
        }
        float bv[4][4];
#pragma unroll
        for (int kk = 0; kk < 4; kk++) {
            float4 tq = *(const float4*)&ct[(k0+kk)*64 + 4*tx];
            bv[kk][0] = tq.x; bv[kk][1] = tq.y; bv[kk][2] = tq.z; bv[kk][3] = tq.w;
        }
#pragma unroll
        for (int i = 0; i < 8; i++)
#pragma unroll
            for (int c = 0; c < 4; c++)
#pragma unroll
                for (int kk = 0; kk < 4; kk++)
                    acc[i][c] += av[i][kk]*bv[kk][c];
    }
#pragma unroll
    for (int i = 0; i < 8; i++) {
        int row = b0 + ty + 16*i;
        size_t off = ((size_t)row*128 + t)*64 + 4*tx;
        float4 vv = {acc[i][0], acc[i][1], acc[i][2], acc[i][3]};
        *(float4*)&out[off] = vv;
    }
}

extern "C" void kernel_launch(void* const* d_in, const int* in_sizes, int n_in,
                              void* d_out, int out_size, void* d_ws, size_t ws_size,
                              hipStream_t stream) {
    const float* x = (const float*)d_in[0];
    const float* tri = (const float*)d_in[1];
    float* out = (float*)d_out;
    float* ws = (float*)d_ws;
    Coefs C = make_coefs();

    hipLaunchKernelGGL(k_zero, dim3(1), dim3(256), 0, stream, ws);
    hipLaunchKernelGGL(k_prep, dim3(1), dim3(256), 0, stream, tri, ws);
    hipLaunchKernelGGL(k_initdense, dim3(64), dim3(256), 0, stream, x, ws);
    hipLaunchKernelGGL(k_initctrl, dim3(1), dim3(1), 0, stream, ws);
    void* args[3] = {(void*)&x, (void*)&ws, (void*)&C};
    hipLaunchCooperativeKernel((void*)k_integrate, dim3(64), dim3(256), args, 0,
                               stream);
    hipLaunchKernelGGL(k_make_theta, dim3(128), dim3(256), 0, stream, ws, C);
    hipLaunchKernelGGL(k_out, dim3(32, 128), dim3(256), 0, stream, x, ws, out);
}

// Round 6
// 3341.175 us; speedup vs baseline: 2.2868x; 1.2340x over previous
//
#include <hip/hip_runtime.h>
#include <hip/hip_cooperative_groups.h>
#include <math.h>

#define HH 4096          // 64*64
#define NSLOT 520        // Phi snapshots (complex, 8192 floats each)
#define MAXATT 512

// ---- ws layout (float offsets) ----
#define OFF_A     0                              // A^0..A^7: 8*4096
#define OFF_PHI   (32768)                        // NSLOT * 8192 (re|im)
#define OFF_RE    (OFF_PHI + NSLOT*8192)         // barrier slots: 2 x 64 u64
#define OFF_EY    (OFF_RE + 4*HH)                // legacy (unused)
#define OFF_Y     (OFF_EY + 2*HH)                // legacy (unused)
#define OFF_PART  (OFF_Y + 1048576)              // legacy
#define OFF_CTRL  (OFF_PART + 64)                // 32 scalars
#define OFF_REC   (OFF_CTRL + 32)                // 128 x 4 (step, tau, h, pad)
#define OFF_THETA (OFF_REC + 512)                // 128 x 4096 (Re Theta_t)

typedef unsigned long long ull;

struct Coefs { float r[8], e[8], pa[8], pb[8], pc[8]; };

// ---------------------------------------------------------------------------
// Host: derive dopri5 polynomial coefficients (verified).
// ---------------------------------------------------------------------------
static Coefs make_coefs() {
    static const double beta[6][6] = {
        {1./5, 0, 0, 0, 0, 0},
        {3./40, 9./40, 0, 0, 0, 0},
        {44./45, -56./15, 32./9, 0, 0, 0},
        {19372./6561, -25360./2187, 64448./6561, -212./729, 0, 0},
        {9017./3168, -355./33, 46732./5247, 49./176, -5103./18656, 0},
        {35./384, 0., 500./1113, 125./192, -2187./6784, 11./84}};
    static const double c_sol[7] = {35./384, 0., 500./1113, 125./192,
                                    -2187./6784, 11./84, 0.};
    static const double b_hat[7] = {1951./21600, 0., 22642./50085, 451./720,
                                    -12231./42400, 649./6300, 1./60};
    static const double c_mid[7] = {
        6025192743./30085553152./2, 0., 51252292925./65400821598./2,
        -2691868925./45128329728./2, 187940372067./1594534317056./2,
        -1776094331./19743644256./2, 11237099./235043384./2};
    double P[8][8] = {{0}};
    P[1][0] = 1.0;
    for (int s = 2; s <= 7; s++) {
        P[s][0] = 1.0;
        for (int l = 1; l < s; l++) {
            double bl = beta[s-2][l-1];
            for (int d = 0; d < 7; d++) P[s][d+1] += bl * P[l][d];
        }
    }
    double R[8] = {0}, E[8] = {0}, M[8] = {0}, WR[8] = {0};
    R[0] = 1.0; M[0] = 1.0;
    for (int s = 1; s <= 7; s++)
        for (int d = 0; d < 7; d++) {
            R[d+1] += c_sol[s-1] * P[s][d];
            E[d+1] += (c_sol[s-1] - b_hat[s-1]) * P[s][d];
            M[d+1] += c_mid[s-1] * P[s][d];
        }
    for (int d = 0; d < 7; d++) WR[d+1] = R[d];
    Coefs c;
    for (int d = 0; d < 8; d++) {
        double W = (d == 1) ? 1.0 : 0.0, I0 = (d == 0) ? 1.0 : 0.0;
        c.r[d] = (float)R[d];
        c.e[d] = (float)E[d];
        c.pa[d] = (float)(-2*W + 2*WR[d] -  8*I0 -  8*R[d] + 16*M[d]);
        c.pb[d] = (float)( 5*W - 3*WR[d] + 18*I0 + 14*R[d] - 32*M[d]);
        c.pc[d] = (float)(-4*W + 1*WR[d] - 11*I0 -  5*R[d] + 16*M[d]);
    }
    return c;
}

// ---------------------------------------------------------------------------
// 64x64 fp32 matmul on LDS operands (256 thr, 4x4 tile per thread). (k_prep)
// ---------------------------------------------------------------------------
__device__ __forceinline__ void mm64(const float* __restrict__ a,
                                     const float* __restrict__ b,
                                     float* __restrict__ dst, int ty, int tx) {
    float acc[4][4];
#pragma unroll
    for (int i = 0; i < 4; i++)
#pragma unroll
        for (int j = 0; j < 4; j++) acc[i][j] = 0.f;
    for (int k = 0; k < 64; k++) {
        float av[4];
#pragma unroll
        for (int i = 0; i < 4; i++) av[i] = a[(4*ty+i)*64 + k];
        const float4 bq = *(const float4*)&b[k*64 + 4*tx];
        float bv[4] = {bq.x, bq.y, bq.z, bq.w};
#pragma unroll
        for (int i = 0; i < 4; i++)
#pragma unroll
            for (int j = 0; j < 4; j++) acc[i][j] += av[i]*bv[j];
    }
#pragma unroll
    for (int i = 0; i < 4; i++)
#pragma unroll
        for (int j = 0; j < 4; j++) dst[(4*ty+i)*64 + 4*tx + j] = acc[i][j];
}

// ---------------------------------------------------------------------------
__global__ __launch_bounds__(256) void k_zero(float* __restrict__ ws) {
    int t = threadIdx.x;
    if (t < 32) ws[OFF_CTRL + t] = 0.f;
    if (t < 256) ws[OFF_RE + t] = 0.f;   // clear 2x64 u64 barrier slots
    if (t < 128) {   // REC defaults: step 0, tau 0, h 1 -> Theta = I
        float* rc = ws + OFF_REC + 4*t;
        rc[0] = 0.f; rc[1] = 0.f; rc[2] = 1.f; rc[3] = 0.f;
    }
}

// Build symmetric A from tril params; A^0..A^7 into ws; Phi slot0 = (I,0).
__global__ __launch_bounds__(256) void k_prep(const float* __restrict__ tri,
                                              float* __restrict__ ws) {
    __shared__ float sA[HH], sB[HH], sC[HH];
    const int tid = threadIdx.x;
    for (int l = tid; l < HH; l += 256) {
        int r = l >> 6, c = l & 63;
        int i = r > c ? r : c, j = r > c ? c : r;
        sA[l] = tri[(i*(i+1))/2 + j];
        float id = (r == c) ? 1.f : 0.f;
        ws[OFF_A + l] = id;                    // A^0 = I
        ws[OFF_PHI + l] = id;                  // Phi0 re = I
        ws[OFF_PHI + HH + l] = 0.f;            // Phi0 im = 0
    }
    __syncthreads();
    for (int l = tid; l < HH; l += 256) ws[OFF_A + HH + l] = sA[l];  // A^1
    const int ty = tid >> 4, tx = tid & 15;
    float* bufs[2] = {sB, sC};
    float* cur = sA;
    for (int d = 2; d <= 7; d++) {
        float* dst = bufs[d & 1];
        mm64(cur, sA, dst, ty, tx);
        __syncthreads();
        for (int l = tid; l < HH; l += 256) ws[OFF_A + d*HH + l] = dst[l];
        __syncthreads();
        cur = dst;
    }
}

// ---------------------------------------------------------------------------
// Init: norms for Hairer initial-step only (y-state lives in k_integrate LDS).
// ---------------------------------------------------------------------------
__global__ __launch_bounds__(256) void k_initdense(const float* __restrict__ x,
                                                   float* __restrict__ ws) {
    __shared__ float xs[64*68];
    __shared__ float m1[HH], m2[HH];
    __shared__ float red[256];
    const int tid = threadIdx.x;
    const int r0 = blockIdx.x * 64;
    const float4* xg = (const float4*)(x + (size_t)r0*64);
    for (int q = tid; q < 1024; q += 256) {
        float4 vv = xg[q];
        *(float4*)&xs[(q>>4)*68 + (q&15)*4] = vv;
    }
    for (int q = tid; q < 1024; q += 256) {
        ((float4*)m1)[q] = ((const float4*)(ws + OFF_A + HH))[q];
        ((float4*)m2)[q] = ((const float4*)(ws + OFF_A + 2*HH))[q];
    }
    __syncthreads();
    const int ty = tid >> 4, tx = tid & 15;
    float a1[4][4], a2[4][4];
#pragma unroll
    for (int i = 0; i < 4; i++)
#pragma unroll
        for (int j = 0; j < 4; j++) { a1[i][j] = 0.f; a2[i][j] = 0.f; }
    for (int k = 0; k < 64; k++) {
        float xv[4];
#pragma unroll
        for (int i = 0; i < 4; i++) xv[i] = xs[(4*ty+i)*68 + k];
        const float4 b1 = *(const float4*)&m1[k*64 + 4*tx];
        const float4 b2 = *(const float4*)&m2[k*64 + 4*tx];
        float bv1[4] = {b1.x, b1.y, b1.z, b1.w};
        float bv2[4] = {b2.x, b2.y, b2.z, b2.w};
#pragma unroll
        for (int i = 0; i < 4; i++)
#pragma unroll
            for (int j = 0; j < 4; j++) {
                a1[i][j] += xv[i]*bv1[j];
                a2[i][j] += xv[i]*bv2[j];
            }
    }
    float s0 = 0.f, s1 = 0.f, s2 = 0.f;
#pragma unroll
    for (int i = 0; i < 4; i++)
#pragma unroll
        for (int j = 0; j < 4; j++) {
            int rr = 4*ty + i, cc = 4*tx + j;
            float xval = xs[rr*68 + cc];
            float sc = 1e-3f * (1.f + fabsf(xval));
            float t0 = xval / sc;      s0 += t0*t0;
            float t1 = a1[i][j] * 1e3f; s1 += t1*t1;
            float t2 = a2[i][j] / sc;  s2 += t2*t2;
        }
    float sums[3] = {s0, s1, s2};
    for (int q = 0; q < 3; q++) {
        red[tid] = sums[q];
        __syncthreads();
        for (int w = 128; w > 0; w >>= 1) {
            if (tid < w) red[tid] += red[tid + w];
            __syncthreads();
        }
        if (tid == 0) atomicAdd(&ws[OFF_CTRL + 10 + q], red[0]);
        __syncthreads();
    }
}

// Hairer initial step (verified).
__global__ void k_initctrl(float* __restrict__ ws) {
    float d0 = sqrtf(ws[OFF_CTRL+10]);
    float d1 = sqrtf(ws[OFF_CTRL+11]);
    float d2 = sqrtf(ws[OFF_CTRL+12]);
    float h0 = ((d0 < 1e-5f) || (d1 < 1e-5f)) ? 1e-6f : 0.01f*d0/d1;
    float h1;
    if ((d1 <= 1e-15f) && (d2 <= 1e-15f)) h1 = fmaxf(1e-6f, h0*1e-3f);
    else h1 = powf(0.01f / fmaxf(d1, d2), 0.2f);
    float dt = fminf(100.f*h0, h1);
    float* cf = ws + OFF_CTRL;
    cf[0] = 1.0f;   // t
    cf[1] = dt;     // h
    cf[2] = 2.0f;   // next target
    float* rc = ws + OFF_REC;   // target 0 = y0: step 0, tau 0
    rc[0] = 0.f; rc[1] = 0.f; rc[2] = 1.f; rc[3] = 0.f;
}

// One complex weighted sum into LDS: smat[0..HH)=re, smat[HH..2HH)=im
// of sum_d coef_d h^d (iA)^d.  (validated: v5)
__device__ __forceinline__ void sums_pair(const float* __restrict__ ws,
                                          float* __restrict__ smat,
                                          float h, int tid,
                                          const float* __restrict__ coef) {
    float w[8];
    float hp = 1.f;
#pragma unroll
    for (int d = 0; d < 8; d++) { w[d] = coef[d]*hp; hp *= h; }
    const float4* A4 = (const float4*)(ws + OFF_A);
#pragma unroll
    for (int g = 0; g < 4; g++) {
        const int q = tid + 256*g;
        float4 re = {0,0,0,0}, im = {0,0,0,0};
#pragma unroll
        for (int d = 0; d < 8; d++) {
            float4 a = A4[d*1024 + q];
            float cw = w[d];
            if ((d & 3) >= 2) cw = -cw;     // i^2=-1, i^3=-i
            if ((d & 1) == 0) {
                re.x += cw*a.x; re.y += cw*a.y; re.z += cw*a.z; re.w += cw*a.w;
            } else {
                im.x += cw*a.x; im.y += cw*a.y; im.z += cw*a.z; im.w += cw*a.w;
            }
        }
        ((float4*)smat)[q] = re;
        ((float4*)(smat + HH))[q] = im;
    }
}

// (y0 @ (Mre + i Mim)) tile: aP = u0@Mre - v0@Mim, aQ = u0@Mim + v0@Mre.
// u0/v0 LDS stride 68 (padded); smat row-major 64.  (validated: v5)
__device__ __forceinline__ void cmm_tile(const float* __restrict__ u0,
                                         const float* __restrict__ v0,
                                         const float* __restrict__ smat,
                                         int ty, int tx,
                                         float aP[4][4], float aQ[4][4]) {
#pragma unroll
    for (int i = 0; i < 4; i++)
#pragma unroll
        for (int j = 0; j < 4; j++) { aP[i][j] = 0.f; aQ[i][j] = 0.f; }
#pragma unroll 2
    for (int k0 = 0; k0 < 64; k0 += 4) {
        float ua[4][4], va[4][4];
#pragma unroll
        for (int i = 0; i < 4; i++) {
            const float4 uq = *(const float4*)&u0[(4*ty+i)*68 + k0];
            const float4 vq = *(const float4*)&v0[(4*ty+i)*68 + k0];
            ua[i][0]=uq.x; ua[i][1]=uq.y; ua[i][2]=uq.z; ua[i][3]=uq.w;
            va[i][0]=vq.x; va[i][1]=vq.y; va[i][2]=vq.z; va[i][3]=vq.w;
        }
#pragma unroll
        for (int kk = 0; kk < 4; kk++) {
            const int k = k0 + kk;
            const float4 br = *(const float4*)&smat[k*64 + 4*tx];
            const float4 bi = *(const float4*)&smat[HH + k*64 + 4*tx];
            const float brv[4] = {br.x, br.y, br.z, br.w};
            const float biv[4] = {bi.x, bi.y, bi.z, bi.w};
#pragma unroll
            for (int i = 0; i < 4; i++) {
                const float ur = ua[i][kk], vr = va[i][kk];
#pragma unroll
                for (int j = 0; j < 4; j++) {
                    aP[i][j] += ur*brv[j] - vr*biv[j];
                    aQ[i][j] += ur*biv[j] + vr*brv[j];
                }
            }
        }
    }
}

// ---------------------------------------------------------------------------
// Integrator v6 = v5 with the grid.sync replaced by a tagged-u64 spin
// barrier with in-band payload:
//  - tid0 posts {tag=iter+1 | f32 partial} to slot[(iter&1)*64+bid]
//    (relaxed, AGENT scope; data in-band in the atomic word).
//  - wave0 (64 lanes = 64 slots) polls, butterfly-sums payloads ->
//    bit-identical S in every block -> replicated ctrl unchanged.
//  - Parity dbuf bounds skew to 1 iter (a block posts N+1 only after all
//    posted N). Phi/REC writes are only read post-kernel.
//  Cooperative launch retained for co-residency (no grid.sync inside).
// ---------------------------------------------------------------------------
__global__ __launch_bounds__(256) void k_integrate(const float* __restrict__ x,
                                                   float* __restrict__ ws,
                                                   Coefs C) {
    __shared__ float u0[64*68], v0[64*68];   // y-state, padded stride 68
    __shared__ float smat[2*HH];             // one complex matrix (re|im)
    __shared__ float phre[256], phim[256];   // this block's 4 Phi rows (bid<16)
    __shared__ float red[4];
    __shared__ float bcf[4];                 // h, acc, done, S
    const int tid = threadIdx.x, bid = blockIdx.x;
    const int ty = tid >> 4, tx = tid & 15;
    const int r0 = bid * 64;
    ull* slots = (ull*)(ws + OFF_RE);        // 2 x 64 tagged slots

    // y0 = (x rows, 0) into LDS
#pragma unroll
    for (int i = 0; i < 4; i++) {
        const float4 xv = *(const float4*)&x[(size_t)(r0 + 4*ty + i)*64 + 4*tx];
        *(float4*)&u0[(4*ty+i)*68 + 4*tx] = xv;
        float4 z = {0.f, 0.f, 0.f, 0.f};
        *(float4*)&v0[(4*ty+i)*68 + 4*tx] = z;
    }
    { int r = tid >> 6, c = tid & 63;
      phre[tid] = (4*bid + r == c) ? 1.f : 0.f; phim[tid] = 0.f; }

    // replicated controller state
    float h    = ws[OFF_CTRL + 1];
    float t_   = ws[OFF_CTRL + 0];
    float ntgt = ws[OFF_CTRL + 2];
    int tgi = 1, na = 0, att = 0;
    __syncthreads();

    for (int iter = 0; iter < MAXATT; iter++) {
        // ---- pass E: err = y0 @ Ec ----
        sums_pair(ws, smat, h, tid, C.e);
        __syncthreads();
        float aE[4][4], aF[4][4];
        cmm_tile(u0, v0, smat, ty, tx, aE, aF);
        __syncthreads();                       // smat reads done
        // ---- pass R: y1 = y0 @ Rc (smat keeps Rc for lazy Phi) ----
        sums_pair(ws, smat, h, tid, C.r);
        __syncthreads();
        float aU[4][4], aV[4][4];
        cmm_tile(u0, v0, smat, ty, tx, aU, aV);
        // ---- error ratio + block reduce ----
        float s = 0.f;
#pragma unroll
        for (int i = 0; i < 4; i++)
#pragma unroll
            for (int j = 0; j < 4; j++) {
                const int off = (4*ty+i)*68 + 4*tx + j;
                const float tu = 1e-3f + 1e-3f*fmaxf(fabsf(u0[off]), fabsf(aU[i][j]));
                const float tv = 1e-3f + 1e-3f*fmaxf(fabsf(v0[off]), fabsf(aV[i][j]));
                const float ru = aE[i][j]/tu, rv = aF[i][j]/tv;
                s += ru*ru + rv*rv;
            }
#pragma unroll
        for (int off = 32; off; off >>= 1) s += __shfl_xor(s, off, 64);
        if ((tid & 63) == 0) red[tid >> 6] = s;
        __syncthreads();
        // ---- spin barrier: post own partial, poll all 64, sum in-band ----
        if (tid == 0) {
            const float part = red[0] + red[1] + red[2] + red[3];
            const ull val = ((ull)(unsigned)(iter + 1) << 32)
                          | (ull)__float_as_uint(part);
            __hip_atomic_store(&slots[(iter & 1)*64 + bid], val,
                               __ATOMIC_RELAXED, __HIP_MEMORY_SCOPE_AGENT);
        }
        if (tid < 64) {
            ull v;
            for (;;) {
                v = __hip_atomic_load(&slots[(iter & 1)*64 + tid],
                                      __ATOMIC_RELAXED, __HIP_MEMORY_SCOPE_AGENT);
                if ((unsigned)(v >> 32) == (unsigned)(iter + 1)) break;
                __builtin_amdgcn_s_sleep(1);
            }
            float p = __uint_as_float((unsigned)v);
#pragma unroll
            for (int off = 32; off; off >>= 1) p += __shfl_xor(p, off, 64);
            if (tid == 0) bcf[3] = p;
        }
        __syncthreads();
        // ---- replicated controller (v5-validated arithmetic) ----
        if (tid == 0) {
            const float S = bcf[3];
            float mer = S / 524288.f;           // mean over raveled (u,v)
            bool acc = (mer <= 1.0f);
            float fac = 0.9f * powf(sqrtf(mer), -0.2f);   // safety*rms^{-1/5}
            float lo = acc ? 1.0f : 0.2f;                 // dfactor
            fac = fminf(10.0f, fmaxf(fac, lo));           // ifactor
            float hnew = h * fac;
            int dn = 0;
            if (acc) {
                float tnew = t_ + h;                      // fp32, as jax
                int step0 = na;
                while (tgi < 128 && ntgt <= tnew) {
                    if (bid == 0) {
                        float* rc = ws + OFF_REC + 4*tgi;
                        rc[0] = (float)step0;
                        rc[1] = (ntgt - t_) / (tnew - t_);
                        rc[2] = h; rc[3] = 0.f;
                    }
                    ntgt += 1.0f;
                    tgi++;
                }
                t_ = tnew;
                if (tgi >= 128) dn = 1;
            }
            att++;
            if (att >= MAXATT || na + (acc ? 1 : 0) + 1 >= NSLOT) dn = 1;
            bcf[0] = hnew; bcf[1] = acc ? 1.f : 0.f; bcf[2] = (float)dn;
        }
        __syncthreads();
        const float hn = bcf[0];
        const bool acc = (bcf[1] != 0.f);
        const bool dn  = (bcf[2] != 0.f);
        // ---- apply accept: y0 <= y1 (LDS); lazy Phi (smat holds Rc) ----
        if (acc) {
#pragma unroll
            for (int i = 0; i < 4; i++)
#pragma unroll
                for (int j = 0; j < 4; j++) {
                    const int off = (4*ty+i)*68 + 4*tx + j;
                    u0[off] = aU[i][j];
                    v0[off] = aV[i][j];
                }
            na++;
        }
        const bool dophi = acc && (bid < 16);
        float nre = 0.f, nim = 0.f;
        if (dophi) {   // Phi_na = Phi_{na-1} @ Rc, rows 4bid..4bid+3
            const int r = tid >> 6, c = tid & 63;
            const float* pr = phre + r*64;
            const float* pi = phim + r*64;
#pragma unroll 8
            for (int k = 0; k < 64; k++) {
                nre += pr[k]*smat[k*64 + c] - pi[k]*smat[HH + k*64 + c];
                nim += pr[k]*smat[HH + k*64 + c] + pi[k]*smat[k*64 + c];
            }
        }
        __syncthreads();   // phre/smat reads done before overwrite
        if (dophi) {
            const int r = tid >> 6, c = tid & 63;
            phre[r*64 + c] = nre; phim[r*64 + c] = nim;
            const size_t go = OFF_PHI + (size_t)na*8192 + (size_t)(4*bid + r)*64 + c;
            ws[go] = nre; ws[go + HH] = nim;
        }
        h = hn;
        if (dn) break;
    }
}

// Theta_t = Phi_step * (tau^4 Pa + tau^3 Pb + tau^2 Pc + tau W + 1)(W), Re only.
__global__ __launch_bounds__(256) void k_make_theta(float* __restrict__ ws,
                                                    Coefs C) {
    __shared__ float sre[HH], simm[HH], pre[HH], pim[HH];
    const int tid = threadIdx.x;
    const int t = blockIdx.x;
    const float* rc = ws + OFF_REC + 4*t;
    int step = (int)rc[0];
    if (step < 0) step = 0;
    if (step >= NSLOT) step = NSLOT - 1;
    const float tau = rc[1], h = rc[2];
    float hp[8];
    hp[0] = 1.f;
#pragma unroll
    for (int d = 1; d < 8; d++) hp[d] = hp[d-1]*h;
    float t2 = tau*tau, t3 = t2*tau, t4 = t3*tau;
    float wre[8], wim[8];
#pragma unroll
    for (int d = 0; d < 8; d++) {
        float sd = t4*C.pa[d] + t3*C.pb[d] + t2*C.pc[d];
        if (d == 1) sd += tau;
        if (d == 0) sd += 1.f;
        float w = sd * hp[d];
        int m = d & 3;
        wre[d] = (m == 0) ? w : (m == 2 ? -w : 0.f);
        wim[d] = (m == 1) ? w : (m == 3 ? -w : 0.f);
    }
    const float* phre = ws + OFF_PHI + (size_t)step*8192;
    const float* phim = phre + HH;
    for (int e = tid; e < HH; e += 256) {
        float are = 0.f, aim = 0.f;
#pragma unroll
        for (int d = 0; d < 8; d++) {
            float ad = ws[OFF_A + d*HH + e];
            are += wre[d]*ad;
            aim += wim[d]*ad;
        }
        sre[e] = are;
        simm[e] = aim;
        pre[e] = phre[e];
        pim[e] = phim[e];
    }
    __syncthreads();
    for (int e = tid; e < HH; e += 256) {
        int rr = e >> 6, cc = e & 63;
        float acc = 0.f;
        for (int k = 0; k < 64; k++)
            acc += pre[rr*64+k]*sre[k*64+cc] - pim[rr*64+k]*simm[k*64+cc];
        ws[OFF_THETA + (size_t)t*HH + e] = acc;
    }
}

// out[b, t, :] = x[b, :] @ Theta_t   (128 rows x one t per block)
__global__ __launch_bounds__(256) void k_out(const float* __restrict__ x,
                                             const float* __restrict__ ws,
                                             float* __restrict__ out) {
    __shared__ float xs[128*68];
    __shared__ float ct[HH];
    const int tid = threadIdx.x;
    const int b0 = blockIdx.x * 128;
    const int t = blockIdx.y;
    const float4* xg4 = (const float4*)(x + (size_t)b0*64);
    for (int i4 = tid; i4 < 2048; i4 += 256) {
        float4 vv = xg4[i4];
        *(float4*)&xs[(i4>>4)*68 + (i4&15)*4] = vv;
    }
    const float4* cg4 = (const float4*)(ws + OFF_THETA + (size_t)t*HH);
    for (int i4 = tid; i4 < 1024; i4 += 256) ((float4*)ct)[i4] = cg4[i4];
    __syncthreads();
    const int ty = tid >> 4, tx = tid & 15;
    float acc[8][4];
#pragma unroll
    for (int i = 0; i < 8; i++)
#pragma unroll
        for (int c = 0; c < 4; c++) acc[i][c] = 0.f;
    for (int kg = 0; kg < 16; kg++) {
        const int k0 = kg*4;
        float av[8][4];
#pragma unroll
        for (int i = 0; i < 8; i++) {
            float4 tq = *(const float4*)&xs[(ty + 16*i)*68 + k0];
            av[i][0] = tq.x; av[i][1] = tq.y; av[i][2] = tq.z; av[i][3] = tq.w;
        }
        float bv[4][4];
#pragma unroll
        for (int kk = 0; kk < 4; kk++) {
            float4 tq = *(const float4*)&ct[(k0+kk)*64 + 4*tx];
            bv[kk][0] = tq.x; bv[kk][1] = tq.y; bv[kk][2] = tq.z; bv[kk][3] = tq.w;
        }
#pragma unroll
        for (int i = 0; i < 8; i++)
#pragma unroll
            for (int c = 0; c < 4; c++)
#pragma unroll
                for (int kk = 0; kk < 4; kk++)
                    acc[i][c] += av[i][kk]*bv[kk][c];
    }
#pragma unroll
    for (int i = 0; i < 8; i++) {
        int row = b0 + ty + 16*i;
        size_t off = ((size_t)row*128 + t)*64 + 4*tx;
        float4 vv = {acc[i][0], acc[i][1], acc[i][2], acc[i][3]};
        *(float4*)&out[off] = vv;
    }
}

extern "C" void kernel_launch(void* const* d_in, const int* in_sizes, int n_in,
                              void* d_out, int out_size, void* d_ws, size_t ws_size,
                              hipStream_t stream) {
    const float* x = (const float*)d_in[0];
    const float* tri = (const float*)d_in[1];
    float* out = (float*)d_out;
    float* ws = (float*)d_ws;
    Coefs C = make_coefs();

    hipLaunchKernelGGL(k_zero, dim3(1), dim3(256), 0, stream, ws);
    hipLaunchKernelGGL(k_prep, dim3(1), dim3(256), 0, stream, tri, ws);
    hipLaunchKernelGGL(k_initdense, dim3(64), dim3(256), 0, stream, x, ws);
    hipLaunchKernelGGL(k_initctrl, dim3(1), dim3(1), 0, stream, ws);
    void* args[3] = {(void*)&x, (void*)&ws, (void*)&C};
    hipLaunchCooperativeKernel((void*)k_integrate, dim3(64), dim3(256), args, 0,
                               stream);
    hipLaunchKernelGGL(k_make_theta, dim3(128), dim3(256), 0, stream, ws, C);
    hipLaunchKernelGGL(k_out, dim3(32, 128), dim3(256), 0, stream, x, ws, out);
}

// Round 8
// 2143.137 us; speedup vs baseline: 3.5651x; 1.5590x over previous
//
#include <hip/hip_runtime.h>
#include <hip/hip_cooperative_groups.h>
#include <math.h>

#define HH 4096          // 64*64
#define NSLOT 520        // Phi snapshots (complex, 8192 floats each)
#define MAXATT 512
#define NBLK 256         // 256 blocks x 16 rows
#define ROWS 16

// ---- ws layout (float offsets) ----
#define OFF_A     0                              // A^0..A^7: 8*4096
#define OFF_PHI   (32768)                        // NSLOT * 8192 (re|im)
#define OFF_RE    (OFF_PHI + NSLOT*8192)         // barrier slots: 2 x 256 u64
#define OFF_EY    (OFF_RE + 4*HH)                // legacy (unused)
#define OFF_Y     (OFF_EY + 2*HH)                // legacy (unused)
#define OFF_PART  (OFF_Y + 1048576)              // legacy
#define OFF_CTRL  (OFF_PART + 64)                // 32 scalars
#define OFF_REC   (OFF_CTRL + 32)                // 128 x 4 (step, tau, h, pad)
#define OFF_THETA (OFF_REC + 512)                // 128 x 4096 (Re Theta_t)

typedef unsigned long long ull;

struct Coefs { float r[8], e[8], pa[8], pb[8], pc[8]; };

// ---------------------------------------------------------------------------
// Host: derive dopri5 polynomial coefficients (verified).
// ---------------------------------------------------------------------------
static Coefs make_coefs() {
    static const double beta[6][6] = {
        {1./5, 0, 0, 0, 0, 0},
        {3./40, 9./40, 0, 0, 0, 0},
        {44./45, -56./15, 32./9, 0, 0, 0},
        {19372./6561, -25360./2187, 64448./6561, -212./729, 0, 0},
        {9017./3168, -355./33, 46732./5247, 49./176, -5103./18656, 0},
        {35./384, 0., 500./1113, 125./192, -2187./6784, 11./84}};
    static const double c_sol[7] = {35./384, 0., 500./1113, 125./192,
                                    -2187./6784, 11./84, 0.};
    static const double b_hat[7] = {1951./21600, 0., 22642./50085, 451./720,
                                    -12231./42400, 649./6300, 1./60};
    static const double c_mid[7] = {
        6025192743./30085553152./2, 0., 51252292925./65400821598./2,
        -2691868925./45128329728./2, 187940372067./1594534317056./2,
        -1776094331./19743644256./2, 11237099./235043384./2};
    double P[8][8] = {{0}};
    P[1][0] = 1.0;
    for (int s = 2; s <= 7; s++) {
        P[s][0] = 1.0;
        for (int l = 1; l < s; l++) {
            double bl = beta[s-2][l-1];
            for (int d = 0; d < 7; d++) P[s][d+1] += bl * P[l][d];
        }
    }
    double R[8] = {0}, E[8] = {0}, M[8] = {0}, WR[8] = {0};
    R[0] = 1.0; M[0] = 1.0;
    for (int s = 1; s <= 7; s++)
        for (int d = 0; d < 7; d++) {
            R[d+1] += c_sol[s-1] * P[s][d];
            E[d+1] += (c_sol[s-1] - b_hat[s-1]) * P[s][d];
            M[d+1] += c_mid[s-1] * P[s][d];
        }
    for (int d = 0; d < 7; d++) WR[d+1] = R[d];
    Coefs c;
    for (int d = 0; d < 8; d++) {
        double W = (d == 1) ? 1.0 : 0.0, I0 = (d == 0) ? 1.0 : 0.0;
        c.r[d] = (float)R[d];
        c.e[d] = (float)E[d];
        c.pa[d] = (float)(-2*W + 2*WR[d] -  8*I0 -  8*R[d] + 16*M[d]);
        c.pb[d] = (float)( 5*W - 3*WR[d] + 18*I0 + 14*R[d] - 32*M[d]);
        c.pc[d] = (float)(-4*W + 1*WR[d] - 11*I0 -  5*R[d] + 16*M[d]);
    }
    return c;
}

// ---------------------------------------------------------------------------
// 64x64 fp32 matmul on LDS operands (256 thr, 4x4 tile per thread). (k_prep)
// ---------------------------------------------------------------------------
__device__ __forceinline__ void mm64(const float* __restrict__ a,
                                     const float* __restrict__ b,
                                     float* __restrict__ dst, int ty, int tx) {
    float acc[4][4];
#pragma unroll
    for (int i = 0; i < 4; i++)
#pragma unroll
        for (int j = 0; j < 4; j++) acc[i][j] = 0.f;
    for (int k = 0; k < 64; k++) {
        float av[4];
#pragma unroll
        for (int i = 0; i < 4; i++) av[i] = a[(4*ty+i)*64 + k];
        const float4 bq = *(const float4*)&b[k*64 + 4*tx];
        float bv[4] = {bq.x, bq.y, bq.z, bq.w};
#pragma unroll
        for (int i = 0; i < 4; i++)
#pragma unroll
            for (int j = 0; j < 4; j++) acc[i][j] += av[i]*bv[j];
    }
#pragma unroll
    for (int i = 0; i < 4; i++)
#pragma unroll
        for (int j = 0; j < 4; j++) dst[(4*ty+i)*64 + 4*tx + j] = acc[i][j];
}

// ---------------------------------------------------------------------------
__global__ __launch_bounds__(256) void k_zero(float* __restrict__ ws) {
    int t = threadIdx.x;
    if (t < 32) ws[OFF_CTRL + t] = 0.f;
    for (int i = t; i < 1024; i += 256) ws[OFF_RE + i] = 0.f;  // 2x256 u64 slots
    if (t < 128) {   // REC defaults: step 0, tau 0, h 1 -> Theta = I
        float* rc = ws + OFF_REC + 4*t;
        rc[0] = 0.f; rc[1] = 0.f; rc[2] = 1.f; rc[3] = 0.f;
    }
}

// Build symmetric A from tril params; A^0..A^7 into ws; Phi slot0 = (I,0).
__global__ __launch_bounds__(256) void k_prep(const float* __restrict__ tri,
                                              float* __restrict__ ws) {
    __shared__ float sA[HH], sB[HH], sC[HH];
    const int tid = threadIdx.x;
    for (int l = tid; l < HH; l += 256) {
        int r = l >> 6, c = l & 63;
        int i = r > c ? r : c, j = r > c ? c : r;
        sA[l] = tri[(i*(i+1))/2 + j];
        float id = (r == c) ? 1.f : 0.f;
        ws[OFF_A + l] = id;                    // A^0 = I
        ws[OFF_PHI + l] = id;                  // Phi0 re = I
        ws[OFF_PHI + HH + l] = 0.f;            // Phi0 im = 0
    }
    __syncthreads();
    for (int l = tid; l < HH; l += 256) ws[OFF_A + HH + l] = sA[l];  // A^1
    const int ty = tid >> 4, tx = tid & 15;
    float* bufs[2] = {sB, sC};
    float* cur = sA;
    for (int d = 2; d <= 7; d++) {
        float* dst = bufs[d & 1];
        mm64(cur, sA, dst, ty, tx);
        __syncthreads();
        for (int l = tid; l < HH; l += 256) ws[OFF_A + d*HH + l] = dst[l];
        __syncthreads();
        cur = dst;
    }
}

// ---------------------------------------------------------------------------
// Init: norms for Hairer initial-step only (y-state lives in k_integrate LDS).
// ---------------------------------------------------------------------------
__global__ __launch_bounds__(256) void k_initdense(const float* __restrict__ x,
                                                   float* __restrict__ ws) {
    __shared__ float xs[64*68];
    __shared__ float m1[HH], m2[HH];
    __shared__ float red[256];
    const int tid = threadIdx.x;
    const int r0 = blockIdx.x * 64;
    const float4* xg = (const float4*)(x + (size_t)r0*64);
    for (int q = tid; q < 1024; q += 256) {
        float4 vv = xg[q];
        *(float4*)&xs[(q>>4)*68 + (q&15)*4] = vv;
    }
    for (int q = tid; q < 1024; q += 256) {
        ((float4*)m1)[q] = ((const float4*)(ws + OFF_A + HH))[q];
        ((float4*)m2)[q] = ((const float4*)(ws + OFF_A + 2*HH))[q];
    }
    __syncthreads();
    const int ty = tid >> 4, tx = tid & 15;
    float a1[4][4], a2[4][4];
#pragma unroll
    for (int i = 0; i < 4; i++)
#pragma unroll
        for (int j = 0; j < 4; j++) { a1[i][j] = 0.f; a2[i][j] = 0.f; }
    for (int k = 0; k < 64; k++) {
        float xv[4];
#pragma unroll
        for (int i = 0; i < 4; i++) xv[i] = xs[(4*ty+i)*68 + k];
        const float4 b1 = *(const float4*)&m1[k*64 + 4*tx];
        const float4 b2 = *(const float4*)&m2[k*64 + 4*tx];
        float bv1[4] = {b1.x, b1.y, b1.z, b1.w};
        float bv2[4] = {b2.x, b2.y, b2.z, b2.w};
#pragma unroll
        for (int i = 0; i < 4; i++)
#pragma unroll
            for (int j = 0; j < 4; j++) {
                a1[i][j] += xv[i]*bv1[j];
                a2[i][j] += xv[i]*bv2[j];
            }
    }
    float s0 = 0.f, s1 = 0.f, s2 = 0.f;
#pragma unroll
    for (int i = 0; i < 4; i++)
#pragma unroll
        for (int j = 0; j < 4; j++) {
            int rr = 4*ty + i, cc = 4*tx + j;
            float xval = xs[rr*68 + cc];
            float sc = 1e-3f * (1.f + fabsf(xval));
            float t0 = xval / sc;      s0 += t0*t0;
            float t1 = a1[i][j] * 1e3f; s1 += t1*t1;
            float t2 = a2[i][j] / sc;  s2 += t2*t2;
        }
    float sums[3] = {s0, s1, s2};
    for (int q = 0; q < 3; q++) {
        red[tid] = sums[q];
        __syncthreads();
        for (int w = 128; w > 0; w >>= 1) {
            if (tid < w) red[tid] += red[tid + w];
            __syncthreads();
        }
        if (tid == 0) atomicAdd(&ws[OFF_CTRL + 10 + q], red[0]);
        __syncthreads();
    }
}

// Hairer initial step (verified).
__global__ void k_initctrl(float* __restrict__ ws) {
    float d0 = sqrtf(ws[OFF_CTRL+10]);
    float d1 = sqrtf(ws[OFF_CTRL+11]);
    float d2 = sqrtf(ws[OFF_CTRL+12]);
    float h0 = ((d0 < 1e-5f) || (d1 < 1e-5f)) ? 1e-6f : 0.01f*d0/d1;
    float h1;
    if ((d1 <= 1e-15f) && (d2 <= 1e-15f)) h1 = fmaxf(1e-6f, h0*1e-3f);
    else h1 = powf(0.01f / fmaxf(d1, d2), 0.2f);
    float dt = fminf(100.f*h0, h1);
    float* cf = ws + OFF_CTRL;
    cf[0] = 1.0f;   // t
    cf[1] = dt;     // h
    cf[2] = 2.0f;   // next target
    float* rc = ws + OFF_REC;   // target 0 = y0: step 0, tau 0
    rc[0] = 0.f; rc[1] = 0.f; rc[2] = 1.f; rc[3] = 0.f;
}

// One complex weighted sum into LDS: smat[0..HH)=re, smat[HH..2HH)=im
// of sum_d coef_d h^d (iA)^d.  (validated: v5/v6)
__device__ __forceinline__ void sums_pair(const float* __restrict__ ws,
                                          float* __restrict__ smat,
                                          float h, int tid,
                                          const float* __restrict__ coef) {
    float w[8];
    float hp = 1.f;
#pragma unroll
    for (int d = 0; d < 8; d++) { w[d] = coef[d]*hp; hp *= h; }
    const float4* A4 = (const float4*)(ws + OFF_A);
#pragma unroll
    for (int g = 0; g < 4; g++) {
        const int q = tid + 256*g;
        float4 re = {0,0,0,0}, im = {0,0,0,0};
#pragma unroll
        for (int d = 0; d < 8; d++) {
            float4 a = A4[d*1024 + q];
            float cw = w[d];
            if ((d & 3) >= 2) cw = -cw;     // i^2=-1, i^3=-i
            if ((d & 1) == 0) {
                re.x += cw*a.x; re.y += cw*a.y; re.z += cw*a.z; re.w += cw*a.w;
            } else {
                im.x += cw*a.x; im.y += cw*a.y; im.z += cw*a.z; im.w += cw*a.w;
            }
        }
        ((float4*)smat)[q] = re;
        ((float4*)(smat + HH))[q] = im;
    }
}

// (y0 @ (Mre + i Mim)) 1-row x 4-col tile for the 16-row slab.
// u0/v0 LDS stride 68; smat row-major 64.
__device__ __forceinline__ void cmm16(const float* __restrict__ u0,
                                      const float* __restrict__ v0,
                                      const float* __restrict__ smat,
                                      int r, int tx,
                                      float aP[4], float aQ[4]) {
#pragma unroll
    for (int j = 0; j < 4; j++) { aP[j] = 0.f; aQ[j] = 0.f; }
#pragma unroll 4
    for (int k0 = 0; k0 < 64; k0 += 4) {
        const float4 uq = *(const float4*)&u0[r*68 + k0];
        const float4 vq = *(const float4*)&v0[r*68 + k0];
        const float uu[4] = {uq.x, uq.y, uq.z, uq.w};
        const float vv[4] = {vq.x, vq.y, vq.z, vq.w};
#pragma unroll
        for (int kk = 0; kk < 4; kk++) {
            const int k = k0 + kk;
            const float4 br = *(const float4*)&smat[k*64 + 4*tx];
            const float4 bi = *(const float4*)&smat[HH + k*64 + 4*tx];
            const float brv[4] = {br.x, br.y, br.z, br.w};
            const float biv[4] = {bi.x, bi.y, bi.z, bi.w};
            const float ur = uu[kk], vr = vv[kk];
#pragma unroll
            for (int j = 0; j < 4; j++) {
                aP[j] += ur*brv[j] - vr*biv[j];
                aQ[j] += ur*biv[j] + vr*brv[j];
            }
        }
    }
}

// ---------------------------------------------------------------------------
// Integrator v7 = v6 row-split 4x: 256 blocks x 16 rows (1 block/CU).
//  Per attempt: sums(E)+E-pass -> sums(R)+R-pass -> ratio/partial ->
//  tagged spin barrier (256 slots; each thread polls one) -> replicated
//  ctrl -> accept(y in LDS) + lazy Phi (blocks 0..15, smat=Rc).
// ---------------------------------------------------------------------------
__global__ __launch_bounds__(256) void k_integrate(const float* __restrict__ x,
                                                   float* __restrict__ ws,
                                                   Coefs C) {
    __shared__ float u0[ROWS*68], v0[ROWS*68]; // y-state, padded stride 68
    __shared__ float smat[2*HH];               // one complex matrix (re|im)
    __shared__ float phre[256], phim[256];     // 4 Phi rows (bid<16)
    __shared__ float red[4];
    __shared__ float bcf[4];                   // h, acc, done, S
    const int tid = threadIdx.x, bid = blockIdx.x;
    const int r = tid >> 4, tx = tid & 15;     // 16 rows x 16 col-groups
    const int r0 = bid * ROWS;
    ull* slots = (ull*)(ws + OFF_RE);          // 2 x 256 tagged slots

    // y0 = (x rows, 0) into LDS
    {
        const float4 xv = *(const float4*)&x[(size_t)(r0 + r)*64 + 4*tx];
        *(float4*)&u0[r*68 + 4*tx] = xv;
        float4 z = {0.f, 0.f, 0.f, 0.f};
        *(float4*)&v0[r*68 + 4*tx] = z;
    }
    { int pr = tid >> 6, c = tid & 63;
      phre[tid] = (4*bid + pr == c) ? 1.f : 0.f; phim[tid] = 0.f; }

    // replicated controller state
    float h    = ws[OFF_CTRL + 1];
    float t_   = ws[OFF_CTRL + 0];
    float ntgt = ws[OFF_CTRL + 2];
    int tgi = 1, na = 0, att = 0;
    __syncthreads();

    for (int iter = 0; iter < MAXATT; iter++) {
        // ---- pass E: err = y0 @ Ec ----
        sums_pair(ws, smat, h, tid, C.e);
        __syncthreads();
        float aE[4], aF[4];
        cmm16(u0, v0, smat, r, tx, aE, aF);
        __syncthreads();                       // smat reads done
        // ---- pass R: y1 = y0 @ Rc (smat keeps Rc for lazy Phi) ----
        sums_pair(ws, smat, h, tid, C.r);
        __syncthreads();
        float aU[4], aV[4];
        cmm16(u0, v0, smat, r, tx, aU, aV);
        // ---- error ratio + block reduce ----
        float s = 0.f;
#pragma unroll
        for (int j = 0; j < 4; j++) {
            const int off = r*68 + 4*tx + j;
            const float tu = 1e-3f + 1e-3f*fmaxf(fabsf(u0[off]), fabsf(aU[j]));
            const float tv = 1e-3f + 1e-3f*fmaxf(fabsf(v0[off]), fabsf(aV[j]));
            const float ru = aE[j]/tu, rv = aF[j]/tv;
            s += ru*ru + rv*rv;
        }
#pragma unroll
        for (int off = 32; off; off >>= 1) s += __shfl_xor(s, off, 64);
        if ((tid & 63) == 0) red[tid >> 6] = s;
        __syncthreads();
        // ---- spin barrier: post partial, all 256 threads poll one slot ----
        if (tid == 0) {
            const float part = red[0] + red[1] + red[2] + red[3];
            const ull val = ((ull)(unsigned)(iter + 1) << 32)
                          | (ull)__float_as_uint(part);
            __hip_atomic_store(&slots[(iter & 1)*256 + bid], val,
                               __ATOMIC_RELAXED, __HIP_MEMORY_SCOPE_AGENT);
        }
        {
            ull v;
            for (;;) {
                v = __hip_atomic_load(&slots[(iter & 1)*256 + tid],
                                      __ATOMIC_RELAXED, __HIP_MEMORY_SCOPE_AGENT);
                if ((unsigned)(v >> 32) == (unsigned)(iter + 1)) break;
                __builtin_amdgcn_s_sleep(1);
            }
            float p = __uint_as_float((unsigned)v);
#pragma unroll
            for (int off = 32; off; off >>= 1) p += __shfl_xor(p, off, 64);
            if ((tid & 63) == 0) red[tid >> 6] = p;
        }
        __syncthreads();
        // ---- replicated controller (validated arithmetic) ----
        if (tid == 0) {
            const float S = red[0] + red[1] + red[2] + red[3];
            float mer = S / 524288.f;           // mean over raveled (u,v)
            bool acc = (mer <= 1.0f);
            float fac = 0.9f * powf(sqrtf(mer), -0.2f);   // safety*rms^{-1/5}
            float lo = acc ? 1.0f : 0.2f;                 // dfactor
            fac = fminf(10.0f, fmaxf(fac, lo));           // ifactor
            float hnew = h * fac;
            int dn = 0;
            if (acc) {
                float tnew = t_ + h;                      // fp32, as jax
                int step0 = na;
                while (tgi < 128 && ntgt <= tnew) {
                    if (bid == 0) {
                        float* rc = ws + OFF_REC + 4*tgi;
                        rc[0] = (float)step0;
                        rc[1] = (ntgt - t_) / (tnew - t_);
                        rc[2] = h; rc[3] = 0.f;
                    }
                    ntgt += 1.0f;
                    tgi++;
                }
                t_ = tnew;
                if (tgi >= 128) dn = 1;
            }
            att++;
            if (att >= MAXATT || na + (acc ? 1 : 0) + 1 >= NSLOT) dn = 1;
            bcf[0] = hnew; bcf[1] = acc ? 1.f : 0.f; bcf[2] = (float)dn;
        }
        __syncthreads();
        const float hn = bcf[0];
        const bool acc = (bcf[1] != 0.f);
        const bool dn  = (bcf[2] != 0.f);
        // ---- apply accept: y0 <= y1 (LDS); lazy Phi (smat holds Rc) ----
        if (acc) {
#pragma unroll
            for (int j = 0; j < 4; j++) {
                const int off = r*68 + 4*tx + j;
                u0[off] = aU[j];
                v0[off] = aV[j];
            }
            na++;
        }
        const bool dophi = acc && (bid < 16);
        float nre = 0.f, nim = 0.f;
        if (dophi) {   // Phi_na = Phi_{na-1} @ Rc, rows 4bid..4bid+3
            const int pr = tid >> 6, c = tid & 63;
            const float* prw = phre + pr*64;
            const float* piw = phim + pr*64;
#pragma unroll 8
            for (int k = 0; k < 64; k++) {
                nre += prw[k]*smat[k*64 + c] - piw[k]*smat[HH + k*64 + c];
                nim += prw[k]*smat[HH + k*64 + c] + piw[k]*smat[k*64 + c];
            }
        }
        __syncthreads();   // phre/smat reads done before overwrite
        if (dophi) {
            const int pr = tid >> 6, c = tid & 63;
            phre[pr*64 + c] = nre; phim[pr*64 + c] = nim;
            const size_t go = OFF_PHI + (size_t)na*8192 + (size_t)(4*bid + pr)*64 + c;
            ws[go] = nre; ws[go + HH] = nim;
        }
        h = hn;
        if (dn) break;
    }
}

// Theta_t = Phi_step * (tau^4 Pa + tau^3 Pb + tau^2 Pc + tau W + 1)(W), Re only.
__global__ __launch_bounds__(256) void k_make_theta(float* __restrict__ ws,
                                                    Coefs C) {
    __shared__ float sre[HH], simm[HH], pre[HH], pim[HH];
    const int tid = threadIdx.x;
    const int t = blockIdx.x;
    const float* rc = ws + OFF_REC + 4*t;
    int step = (int)rc[0];
    if (step < 0) step = 0;
    if (step >= NSLOT) step = NSLOT - 1;
    const float tau = rc[1], h = rc[2];
    float hp[8];
    hp[0] = 1.f;
#pragma unroll
    for (int d = 1; d < 8; d++) hp[d] = hp[d-1]*h;
    float t2 = tau*tau, t3 = t2*tau, t4 = t3*tau;
    float wre[8], wim[8];
#pragma unroll
    for (int d = 0; d < 8; d++) {
        float sd = t4*C.pa[d] + t3*C.pb[d] + t2*C.pc[d];
        if (d == 1) sd += tau;
        if (d == 0) sd += 1.f;
        float w = sd * hp[d];
        int m = d & 3;
        wre[d] = (m == 0) ? w : (m == 2 ? -w : 0.f);
        wim[d] = (m == 1) ? w : (m == 3 ? -w : 0.f);
    }
    const float* phre = ws + OFF_PHI + (size_t)step*8192;
    const float* phim = phre + HH;
    for (int e = tid; e < HH; e += 256) {
        float are = 0.f, aim = 0.f;
#pragma unroll
        for (int d = 0; d < 8; d++) {
            float ad = ws[OFF_A + d*HH + e];
            are += wre[d]*ad;
            aim += wim[d]*ad;
        }
        sre[e] = are;
        simm[e] = aim;
        pre[e] = phre[e];
        pim[e] = phim[e];
    }
    __syncthreads();
    for (int e = tid; e < HH; e += 256) {
        int rr = e >> 6, cc = e & 63;
        float acc = 0.f;
        for (int k = 0; k < 64; k++)
            acc += pre[rr*64+k]*sre[k*64+cc] - pim[rr*64+k]*simm[k*64+cc];
        ws[OFF_THETA + (size_t)t*HH + e] = acc;
    }
}

// out[b, t, :] = x[b, :] @ Theta_t   (128 rows x one t per block)
__global__ __launch_bounds__(256) void k_out(const float* __restrict__ x,
                                             const float* __restrict__ ws,
                                             float* __restrict__ out) {
    __shared__ float xs[128*68];
    __shared__ float ct[HH];
    const int tid = threadIdx.x;
    const int b0 = blockIdx.x * 128;
    const int t = blockIdx.y;
    const float4* xg4 = (const float4*)(x + (size_t)b0*64);
    for (int i4 = tid; i4 < 2048; i4 += 256) {
        float4 vv = xg4[i4];
        *(float4*)&xs[(i4>>4)*68 + (i4&15)*4] = vv;
    }
    const float4* cg4 = (const float4*)(ws + OFF_THETA + (size_t)t*HH);
    for (int i4 = tid; i4 < 1024; i4 += 256) ((float4*)ct)[i4] = cg4[i4];
    __syncthreads();
    const int ty = tid >> 4, tx = tid & 15;
    float acc[8][4];
#pragma unroll
    for (int i = 0; i < 8; i++)
#pragma unroll
        for (int c = 0; c < 4; c++) acc[i][c] = 0.f;
    for (int kg = 0; kg < 16; kg++) {
        const int k0 = kg*4;
        float av[8][4];
#pragma unroll
        for (int i = 0; i < 8; i++) {
            float4 tq = *(const float4*)&xs[(ty + 16*i)*68 + k0];
            av[i][0] = tq.x; av[i][1] = tq.y; av[i][2] = tq.z; av[i][3] = tq.w;
        }
        float bv[4][4];
#pragma unroll
        for (int kk = 0; kk < 4; kk++) {
            float4 tq = *(const float4*)&ct[(k0+kk)*64 + 4*tx];
            bv[kk][0] = tq.x; bv[kk][1] = tq.y; bv[kk][2] = tq.z; bv[kk][3] = tq.w;
        }
#pragma unroll
        for (int i = 0; i < 8; i++)
#pragma unroll
            for (int c = 0; c < 4; c++)
#pragma unroll
                for (int kk = 0; kk < 4; kk++)
                    acc[i][c] += av[i][kk]*bv[kk][c];
    }
#pragma unroll
    for (int i = 0; i < 8; i++) {
        int row = b0 + ty + 16*i;
        size_t off = ((size_t)row*128 + t)*64 + 4*tx;
        float4 vv = {acc[i][0], acc[i][1], acc[i][2], acc[i][3]};
        *(float4*)&out[off] = vv;
    }
}

extern "C" void kernel_launch(void* const* d_in, const int* in_sizes, int n_in,
                              void* d_out, int out_size, void* d_ws, size_t ws_size,
                              hipStream_t stream) {
    const float* x = (const float*)d_in[0];
    const float* tri = (const float*)d_in[1];
    float* out = (float*)d_out;
    float* ws = (float*)d_ws;
    Coefs C = make_coefs();

    hipLaunchKernelGGL(k_zero, dim3(1), dim3(256), 0, stream, ws);
    hipLaunchKernelGGL(k_prep, dim3(1), dim3(256), 0, stream, tri, ws);
    hipLaunchKernelGGL(k_initdense, dim3(64), dim3(256), 0, stream, x, ws);
    hipLaunchKernelGGL(k_initctrl, dim3(1), dim3(1), 0, stream, ws);
    void* args[3] = {(void*)&x, (void*)&ws, (void*)&C};
    hipLaunchCooperativeKernel((void*)k_integrate, dim3(NBLK), dim3(256), args, 0,
                               stream);
    hipLaunchKernelGGL(k_make_theta, dim3(128), dim3(256), 0, stream, ws, C);
    hipLaunchKernelGGL(k_out, dim3(32, 128), dim3(256), 0, stream, x, ws, out);
}